// Round 13
// baseline (254.899 us; speedup 1.0000x reference)
//
#include <hip/hip_runtime.h>

#define N_NODES 100000
#define N_EDGESC 800000
#define NGRAPH 128
#define DIN 84
#define DHID 840
#define DF1 1024
#define DOUTC 384
#define PBLK3 1563  // ceil(N_NODES/64) row-tiles
#define KP1 1696    // 2*DHID padded to x32
#define NBUCK 391   // ceil(N_NODES/256)
#define EPB 2048    // edges per bucketing block (grid 391)
#define XSTR 96     // padded row stride (192B = 3 aligned lines)

// k_prep block ranges
#define XBF_B 9375  // ceil(N_NODES*24/256)
#define W2T_B 336   // ceil(896*96/256)
#define W1T_B 36    // ceil(96*96/256)
#define CNT_B 49    // ceil(N_NODES/2048)
#define G1_B  1696  // (KP1/32)*(DF1/32)
#define G2_B  384   // (DF1/32)*(DOUTC/32)
#define PREP_B (XBF_B + W2T_B + W1T_B + CNT_B + G1_B + G2_B)

typedef __attribute__((ext_vector_type(4))) float f32x4;
typedef __attribute__((ext_vector_type(8))) short bf16x8;

__device__ __forceinline__ unsigned short f2bf(float f) {
  union { float f; unsigned int u; } v; v.f = f;
  unsigned int r = v.u + 0x7FFFu + ((v.u >> 16) & 1u);
  return (unsigned short)(r >> 16);
}
__device__ __forceinline__ float bf2f(unsigned short h) {
  union { unsigned int u; float f; } v; v.u = ((unsigned int)h) << 16;
  return v.f;
}
__device__ __forceinline__ f32x4 bfq(uint2 p) {
  f32x4 r;
  r.x = bf2f((unsigned short)(p.x & 0xffff)); r.y = bf2f((unsigned short)(p.x >> 16));
  r.z = bf2f((unsigned short)(p.y & 0xffff)); r.w = bf2f((unsigned short)(p.y >> 16));
  return r;
}

// ---------------- bucketed CSR build ----------------
__global__ __launch_bounds__(256) void k_bhist(const int* __restrict__ dst, int* __restrict__ bcnt) {
  __shared__ int h[NBUCK];
  int t = threadIdx.x;
  for (int i = t; i < NBUCK; i += 256) h[i] = 0;
  __syncthreads();
  int base = blockIdx.x * EPB;
  int e1 = min(base + EPB, N_EDGESC);
  for (int e = base + t; e < e1; e += 256)
    atomicAdd(&h[dst[e] >> 8], 1);
  __syncthreads();
  for (int i = t; i < NBUCK; i += 256) if (h[i]) atomicAdd(&bcnt[i], h[i]);
}

__global__ __launch_bounds__(512) void k_bscan(const int* __restrict__ bcnt, int* __restrict__ boff,
                                               int* __restrict__ bcur) {
  __shared__ int sd[512];
  int t = threadIdx.x;
  int v = (t < NBUCK) ? bcnt[t] : 0;
  sd[t] = v; __syncthreads();
  for (int off = 1; off < 512; off <<= 1) {
    int add = (t >= off) ? sd[t - off] : 0;
    __syncthreads();
    sd[t] += add;
    __syncthreads();
  }
  if (t <= NBUCK) {
    boff[t] = sd[t] - v;
    if (t < NBUCK) bcur[t] = sd[t] - v;
  }
}

__global__ __launch_bounds__(256) void k_bfill(const int* __restrict__ src, const int* __restrict__ dst,
                                               int* __restrict__ bcur, unsigned int* __restrict__ rec) {
  __shared__ int hcnt[NBUCK];
  __shared__ int hbase[NBUCK];
  int t = threadIdx.x;
  int e0 = blockIdx.x * EPB;
  int e1 = min(e0 + EPB, N_EDGESC);
  for (int i = t; i < NBUCK; i += 256) hcnt[i] = 0;
  __syncthreads();
  for (int e = e0 + t; e < e1; e += 256)
    atomicAdd(&hcnt[dst[e] >> 8], 1);
  __syncthreads();
  for (int i = t; i < NBUCK; i += 256) {
    int c = hcnt[i];
    hbase[i] = c ? atomicAdd(&bcur[i], c) : 0;
  }
  __syncthreads();
  for (int i = t; i < NBUCK; i += 256) hcnt[i] = 0;
  __syncthreads();
  for (int e = e0 + t; e < e1; e += 256) {
    int d = dst[e];
    int b = d >> 8;
    int r = atomicAdd(&hcnt[b], 1);
    rec[hbase[b] + r] = ((unsigned int)(d & 255) << 24) | (unsigned int)src[e];
  }
}

__global__ __launch_bounds__(256) void k_bsort(const unsigned int* __restrict__ rec, const int* __restrict__ boff,
                                               int* __restrict__ rowptr, int* __restrict__ csr) {
  __shared__ int lcnt[256];
  __shared__ int lcur[256];
  int b = blockIdx.x, t = threadIdx.x;
  int e0 = boff[b], e1 = boff[b + 1];
  lcnt[t] = 0;
  __syncthreads();
  for (int i = e0 + t; i < e1; i += 256) atomicAdd(&lcnt[rec[i] >> 24], 1);
  __syncthreads();
  int v = lcnt[t];
  for (int off = 1; off < 256; off <<= 1) {
    int add = (t >= off) ? lcnt[t - off] : 0;
    __syncthreads();
    lcnt[t] += add;
    __syncthreads();
  }
  int excl = lcnt[t] - v;
  int node = b * 256 + t;
  if (node < N_NODES) rowptr[node] = e0 + excl;
  lcur[t] = e0 + excl;
  if (b == NBUCK - 1 && t == 0) rowptr[N_NODES] = N_EDGESC;
  __syncthreads();
  for (int i = e0 + t; i < e1; i += 256) {
    unsigned int r = rec[i];
    int d = r >> 24;
    int pos = atomicAdd(&lcur[d], 1);
    csr[pos] = (int)(r & 0xFFFFFFu);
  }
}

// ---------------- fused prep: xbf | w2t | w1t | counts | wsplit(Wg1) | wsplit(Wg2) --------
__global__ __launch_bounds__(256) void k_prep(const float* __restrict__ x, unsigned short* __restrict__ xb,
                                              const float* __restrict__ W2, unsigned short* __restrict__ w2t,
                                              const float* __restrict__ W1, unsigned short* __restrict__ w1h,
                                              unsigned short* __restrict__ w1l,
                                              const int* __restrict__ batch, int* __restrict__ cnt,
                                              const float* __restrict__ Wg1, unsigned short* __restrict__ g1h,
                                              unsigned short* __restrict__ g1l,
                                              const float* __restrict__ Wg2, unsigned short* __restrict__ g2h,
                                              unsigned short* __restrict__ g2l) {
  __shared__ float tile[32][33];
  __shared__ int h[NGRAPH];
  int b = blockIdx.x, t = threadIdx.x;

  if (b < XBF_B) {
    int idx = b * 256 + t;
    if (idx >= N_NODES * 24) return;
    int r = idx / 24, c = idx - r * 24;
    uint2 p = {0u, 0u};
    if (c < 21) {
      f32x4 v = *(const f32x4*)&x[r * DIN + c * 4];
      p.x = (unsigned int)f2bf(v.x) | ((unsigned int)f2bf(v.y) << 16);
      p.y = (unsigned int)f2bf(v.z) | ((unsigned int)f2bf(v.w) << 16);
    }
    *(uint2*)&xb[r * XSTR + c * 4] = p;
    return;
  }
  b -= XBF_B;
  if (b < W2T_B) {
    int idx = b * 256 + t;
    if (idx >= 896 * 96) return;
    int n = idx / 96, k = idx % 96;
    float v = (n < DHID && k < DIN) ? W2[k * DHID + n] : 0.f;
    w2t[idx] = f2bf(v);
    return;
  }
  b -= W2T_B;
  if (b < W1T_B) {
    int idx = b * 256 + t;
    if (idx >= 96 * 96) return;
    int n = idx / 96, k = idx % 96;
    float v = (n < DIN && k < DIN) ? W1[k * DIN + n] : 0.f;
    unsigned short hh = f2bf(v);
    w1h[idx] = hh;
    w1l[idx] = f2bf(v - bf2f(hh));
    return;
  }
  b -= W1T_B;
  if (b < CNT_B) {
    if (t < NGRAPH) h[t] = 0;
    __syncthreads();
    int base = b * 2048;
    for (int j = 0; j < 8; j++) {
      int i = base + j * 256 + t;
      if (i < N_NODES) atomicAdd(&h[batch[i]], 1);
    }
    __syncthreads();
    if (t < NGRAPH && h[t] > 0) atomicAdd(&cnt[t], h[t]);
    return;
  }
  b -= CNT_B;
  const float* W; unsigned short *wh, *wl; int K, KPAD, N, vb;
  if (b < G1_B) { W = Wg1; wh = g1h; wl = g1l; K = 2 * DHID; KPAD = KP1; N = DF1; vb = b; }
  else          { W = Wg2; wh = g2h; wl = g2l; K = DF1; KPAD = DF1; N = DOUTC; vb = b - G1_B; }
  int kt = vb % (KPAD / 32), nt2 = vb / (KPAD / 32);
  int k0 = kt * 32, n0 = nt2 * 32;
  int r = t >> 3, c4 = (t & 7) * 4;
  int k = k0 + r;
  f32x4 v = {0.f, 0.f, 0.f, 0.f};
  if (k < K) v = *(const f32x4*)&W[(size_t)k * N + n0 + c4];
  tile[r][c4 + 0] = v.x; tile[r][c4 + 1] = v.y; tile[r][c4 + 2] = v.z; tile[r][c4 + 3] = v.w;
  __syncthreads();
  int n = t >> 3;
  float f0 = tile[c4 + 0][n], f1 = tile[c4 + 1][n], f2 = tile[c4 + 2][n], f3 = tile[c4 + 3][n];
  unsigned short h0 = f2bf(f0), h1_ = f2bf(f1), h2_ = f2bf(f2), h3_ = f2bf(f3);
  uint2 ph, pl;
  ph.x = (unsigned int)h0 | ((unsigned int)h1_ << 16);
  ph.y = (unsigned int)h2_ | ((unsigned int)h3_ << 16);
  pl.x = (unsigned int)f2bf(f0 - bf2f(h0)) | ((unsigned int)f2bf(f1 - bf2f(h1_)) << 16);
  pl.y = (unsigned int)f2bf(f2 - bf2f(h2_)) | ((unsigned int)f2bf(f3 - bf2f(h3_)) << 16);
  *(uint2*)&wh[(size_t)(n0 + n) * KPAD + k0 + c4] = ph;
  *(uint2*)&wl[(size_t)(n0 + n) * KPAD + k0 + c4] = pl;
}

// ---------------- agg1c: bf16 gather (stride 96) -> hi/lo bf16 out (stride 96) -----------
// 3 nodes per 64-lane wave, 12 nodes/block (full gather parallelism). Lane 63 zeroes the
// K-pad cols 84..95 of the wave's 3 rows in both buffers. Split arithmetic identical to
// the old agg1b(f32)->conv1m(split) path -> bit-identical results.
__global__ __launch_bounds__(256) void k_agg1c(const unsigned short* __restrict__ xb,
                                               const int* __restrict__ rowptr,
                                               const int* __restrict__ csr,
                                               unsigned short* __restrict__ aggh,
                                               unsigned short* __restrict__ aggl) {
  int t = threadIdx.x;
  int wv = t >> 6, l = t & 63;
  int grp = (l >= 42) ? 2 : (l >= 21 ? 1 : 0);
  int li = l - grp * 21;
  int node = blockIdx.x * 12 + wv * 3 + grp;
  bool act = (li < 21) && (node < N_NODES);
  if (l == 63) {   // zero pads for this wave's 3 rows
    uint2 z = {0u, 0u};
    for (int g = 0; g < 3; g++) {
      int nd = blockIdx.x * 12 + wv * 3 + g;
      if (nd < N_NODES) {
        *(uint2*)&aggh[nd * XSTR + 84] = z; *(uint2*)&aggh[nd * XSTR + 88] = z; *(uint2*)&aggh[nd * XSTR + 92] = z;
        *(uint2*)&aggl[nd * XSTR + 84] = z; *(uint2*)&aggl[nd * XSTR + 88] = z; *(uint2*)&aggl[nd * XSTR + 92] = z;
      }
    }
  }
  int nclamp = min(node, N_NODES - 1);
  int r0 = rowptr[nclamp];
  int r1 = act ? rowptr[nclamp + 1] : r0;
  f32x4 a = {0.f, 0.f, 0.f, 0.f};
  if (act) a = bfq(*(const uint2*)&xb[nclamp * XSTR + li * 4]);
  int e = r0;
  for (; e + 8 <= r1; e += 8) {
    int s0 = csr[e], s1 = csr[e + 1], s2 = csr[e + 2], s3 = csr[e + 3];
    int s4 = csr[e + 4], s5 = csr[e + 5], s6 = csr[e + 6], s7 = csr[e + 7];
    uint2 q0 = *(const uint2*)&xb[s0 * XSTR + li * 4];
    uint2 q1 = *(const uint2*)&xb[s1 * XSTR + li * 4];
    uint2 q2 = *(const uint2*)&xb[s2 * XSTR + li * 4];
    uint2 q3 = *(const uint2*)&xb[s3 * XSTR + li * 4];
    uint2 q4 = *(const uint2*)&xb[s4 * XSTR + li * 4];
    uint2 q5 = *(const uint2*)&xb[s5 * XSTR + li * 4];
    uint2 q6 = *(const uint2*)&xb[s6 * XSTR + li * 4];
    uint2 q7 = *(const uint2*)&xb[s7 * XSTR + li * 4];
    a += ((bfq(q0) + bfq(q1)) + (bfq(q2) + bfq(q3))) + ((bfq(q4) + bfq(q5)) + (bfq(q6) + bfq(q7)));
  }
  for (; e + 4 <= r1; e += 4) {
    int s0 = csr[e], s1 = csr[e + 1], s2 = csr[e + 2], s3 = csr[e + 3];
    uint2 q0 = *(const uint2*)&xb[s0 * XSTR + li * 4];
    uint2 q1 = *(const uint2*)&xb[s1 * XSTR + li * 4];
    uint2 q2 = *(const uint2*)&xb[s2 * XSTR + li * 4];
    uint2 q3 = *(const uint2*)&xb[s3 * XSTR + li * 4];
    a += (bfq(q0) + bfq(q1)) + (bfq(q2) + bfq(q3));
  }
  for (; e < r1; e++) {
    int s = csr[e];
    a += bfq(*(const uint2*)&xb[s * XSTR + li * 4]);
  }
  if (act) {
    unsigned short h0 = f2bf(a.x), h1_ = f2bf(a.y), h2_ = f2bf(a.z), h3_ = f2bf(a.w);
    uint2 ph, pl;
    ph.x = (unsigned int)h0 | ((unsigned int)h1_ << 16);
    ph.y = (unsigned int)h2_ | ((unsigned int)h3_ << 16);
    pl.x = (unsigned int)f2bf(a.x - bf2f(h0)) | ((unsigned int)f2bf(a.y - bf2f(h1_)) << 16);
    pl.y = (unsigned int)f2bf(a.z - bf2f(h2_)) | ((unsigned int)f2bf(a.w - bf2f(h3_)) << 16);
    *(uint2*)&aggh[node * XSTR + li * 4] = ph;
    *(uint2*)&aggl[node * XSTR + li * 4] = pl;
  }
}

// ---------------- conv1m2: MFMA from global hi/lo A (no LDS), h1b bf16 out ----------------
__global__ __launch_bounds__(256) void k_conv1m2(const unsigned short* __restrict__ aggh,
                                                 const unsigned short* __restrict__ aggl,
                                                 const unsigned short* __restrict__ w1h,
                                                 const unsigned short* __restrict__ w1l,
                                                 const float* __restrict__ b1,
                                                 unsigned short* __restrict__ h1b) {
  int t = threadIdx.x;
  int m0 = blockIdx.x * 64;
  int wv = t >> 6, l = t & 63;
  int lr = l & 15, lk = (l >> 4) * 8;
  int row = m0 + wv * 16 + lr;
  bool inb = row < N_NODES;
  bf16x8 ah[3], al[3];
  #pragma unroll
  for (int kk = 0; kk < 3; kk++) {
    bf16x8 vh = {0, 0, 0, 0, 0, 0, 0, 0};
    bf16x8 vl = {0, 0, 0, 0, 0, 0, 0, 0};
    if (inb) {
      vh = *(const bf16x8*)&aggh[(size_t)row * XSTR + lk + kk * 32];
      vl = *(const bf16x8*)&aggl[(size_t)row * XSTR + lk + kk * 32];
    }
    ah[kk] = vh; al[kk] = vl;
  }
  #pragma unroll
  for (int nt = 0; nt < 6; nt++) {
    f32x4 acc = {0.f, 0.f, 0.f, 0.f};
    #pragma unroll
    for (int kk = 0; kk < 3; kk++) {
      bf16x8 bh = *(const bf16x8*)&w1h[(nt * 16 + lr) * 96 + lk + kk * 32];
      bf16x8 bl = *(const bf16x8*)&w1l[(nt * 16 + lr) * 96 + lk + kk * 32];
      acc = __builtin_amdgcn_mfma_f32_16x16x32_bf16(ah[kk], bh, acc, 0, 0, 0);
      acc = __builtin_amdgcn_mfma_f32_16x16x32_bf16(al[kk], bh, acc, 0, 0, 0);
      acc = __builtin_amdgcn_mfma_f32_16x16x32_bf16(ah[kk], bl, acc, 0, 0, 0);
    }
    int col = nt * 16 + lr;
    if (col < DIN) {
      float bias = b1[col];
      int rbase = m0 + wv * 16 + (l >> 4) * 4;
      #pragma unroll
      for (int j = 0; j < 4; j++) {
        if (rbase + j < N_NODES)
          h1b[(rbase + j) * XSTR + col] = f2bf(fmaxf(acc[j] + bias, 0.f));
      }
    }
  }
}

// ---------------- agg2: bf16 in (stride 96), bf16 out cols 0..83 (stride 96) -------------
__global__ __launch_bounds__(256) void k_agg2(const unsigned short* __restrict__ h1b, const int* __restrict__ rowptr,
                                              const int* __restrict__ csr, unsigned short* __restrict__ out) {
  int t = threadIdx.x;
  int wv = t >> 6, l = t & 63;
  int grp = (l >= 42) ? 2 : (l >= 21 ? 1 : 0);
  int li = l - grp * 21;
  int node = blockIdx.x * 12 + wv * 3 + grp;
  bool act = (li < 21) && (node < N_NODES);
  int nclamp = min(node, N_NODES - 1);
  int r0 = rowptr[nclamp];
  int r1 = act ? rowptr[nclamp + 1] : r0;
  f32x4 a = {0.f, 0.f, 0.f, 0.f};
  if (act) a = bfq(*(const uint2*)&h1b[nclamp * XSTR + li * 4]);
  int e = r0;
  for (; e + 8 <= r1; e += 8) {
    int s0 = csr[e], s1 = csr[e + 1], s2 = csr[e + 2], s3 = csr[e + 3];
    int s4 = csr[e + 4], s5 = csr[e + 5], s6 = csr[e + 6], s7 = csr[e + 7];
    uint2 q0 = *(const uint2*)&h1b[s0 * XSTR + li * 4];
    uint2 q1 = *(const uint2*)&h1b[s1 * XSTR + li * 4];
    uint2 q2 = *(const uint2*)&h1b[s2 * XSTR + li * 4];
    uint2 q3 = *(const uint2*)&h1b[s3 * XSTR + li * 4];
    uint2 q4 = *(const uint2*)&h1b[s4 * XSTR + li * 4];
    uint2 q5 = *(const uint2*)&h1b[s5 * XSTR + li * 4];
    uint2 q6 = *(const uint2*)&h1b[s6 * XSTR + li * 4];
    uint2 q7 = *(const uint2*)&h1b[s7 * XSTR + li * 4];
    a += ((bfq(q0) + bfq(q1)) + (bfq(q2) + bfq(q3))) + ((bfq(q4) + bfq(q5)) + (bfq(q6) + bfq(q7)));
  }
  for (; e + 4 <= r1; e += 4) {
    int s0 = csr[e], s1 = csr[e + 1], s2 = csr[e + 2], s3 = csr[e + 3];
    uint2 q0 = *(const uint2*)&h1b[s0 * XSTR + li * 4];
    uint2 q1 = *(const uint2*)&h1b[s1 * XSTR + li * 4];
    uint2 q2 = *(const uint2*)&h1b[s2 * XSTR + li * 4];
    uint2 q3 = *(const uint2*)&h1b[s3 * XSTR + li * 4];
    a += (bfq(q0) + bfq(q1)) + (bfq(q2) + bfq(q3));
  }
  for (; e < r1; e++) {
    int s = csr[e];
    a += bfq(*(const uint2*)&h1b[s * XSTR + li * 4]);
  }
  if (act) {
    uint2 p;
    p.x = (unsigned int)f2bf(a.x) | ((unsigned int)f2bf(a.y) << 16);
    p.y = (unsigned int)f2bf(a.z) | ((unsigned int)f2bf(a.w) << 16);
    *(uint2*)&out[node * XSTR + li * 4] = p;
  }
}

// ---------------- conv2 + pooling stage 1: 64-row tiles x 2 column-halves ----------------
__global__ __launch_bounds__(256) void k_conv2pool4(const unsigned short* __restrict__ aggb,
                                                    const unsigned short* __restrict__ w2t,
                                                    const float* __restrict__ b2,
                                                    const int* __restrict__ batch,
                                                    float2* __restrict__ pm, float2* __restrict__ pm1,
                                                    int* __restrict__ blkg,
                                                    int* __restrict__ maxb, float* __restrict__ sump) {
  constexpr int LDA = 104;
  __shared__ __align__(16) unsigned short At[64 * LDA];
  int t = threadIdx.x;
  int w = t >> 6, l = t & 63;
  int b = blockIdx.x >> 1;
  int half = blockIdx.x & 1;
  int m0 = b * 64;
  int lr = l & 15, hi = l >> 4, lk = hi * 8;

  for (int idx = t; idx < 64 * 12; idx += 256) {
    int r = idx / 12, c = idx - r * 12;
    uint4 v = {0u, 0u, 0u, 0u};
    int row = m0 + r;
    if (row < N_NODES) v = *(const uint4*)&aggb[row * XSTR + c * 8];
    *(uint4*)&At[r * LDA + c * 8] = v;
  }
  int g0 = batch[m0];
  int g1 = batch[min(m0 + 63, N_NODES - 1)];
  bool fast = (g0 == g1) && (m0 + 63 < N_NODES);
  __syncthreads();

  bf16x8 afr[4][3];
  #pragma unroll
  for (int rg = 0; rg < 4; rg++)
    #pragma unroll
    for (int kk = 0; kk < 3; kk++)
      afr[rg][kk] = *(bf16x8*)&At[(rg * 16 + lr) * LDA + lk + kk * 32];

  int pbase = half * 28 + w * 7;

  if (fast) {
    for (int i = 0; i < 7; i++) {
      int c = (pbase + i) * 16 + lr;
      const unsigned short* bp = &w2t[c * 96 + lk];
      bf16x8 b0v = *(const bf16x8*)(bp);
      bf16x8 b1v = *(const bf16x8*)(bp + 32);
      bf16x8 b2v = *(const bf16x8*)(bp + 64);
      float bias = (c < DHID) ? b2[c] : 0.f;
      float mx = 0.f, sm = 0.f;
      #pragma unroll
      for (int rg = 0; rg < 4; rg++) {
        f32x4 a_ = {0.f, 0.f, 0.f, 0.f};
        a_ = __builtin_amdgcn_mfma_f32_16x16x32_bf16(afr[rg][0], b0v, a_, 0, 0, 0);
        a_ = __builtin_amdgcn_mfma_f32_16x16x32_bf16(afr[rg][1], b1v, a_, 0, 0, 0);
        a_ = __builtin_amdgcn_mfma_f32_16x16x32_bf16(afr[rg][2], b2v, a_, 0, 0, 0);
        float v0 = fmaxf(a_[0] + bias, 0.f);
        float v1 = fmaxf(a_[1] + bias, 0.f);
        float v2 = fmaxf(a_[2] + bias, 0.f);
        float v3 = fmaxf(a_[3] + bias, 0.f);
        mx = fmaxf(mx, fmaxf(fmaxf(v0, v1), fmaxf(v2, v3)));
        sm += (v0 + v1) + (v2 + v3);
      }
      mx = fmaxf(mx, __shfl_xor(mx, 16)); sm += __shfl_xor(sm, 16);
      mx = fmaxf(mx, __shfl_xor(mx, 32)); sm += __shfl_xor(sm, 32);
      if (hi == 0 && c < DHID) pm[(size_t)b * DHID + c] = make_float2(mx, sm);
    }
  } else {
    int grow[4][4];
    #pragma unroll
    for (int rg = 0; rg < 4; rg++)
      #pragma unroll
      for (int j = 0; j < 4; j++) {
        int row = m0 + rg * 16 + hi * 4 + j;
        grow[rg][j] = (row < N_NODES) ? batch[row] : -1;
      }
    for (int i = 0; i < 7; i++) {
      int c = (pbase + i) * 16 + lr;
      const unsigned short* bp = &w2t[c * 96 + lk];
      bf16x8 b0v = *(const bf16x8*)(bp);
      bf16x8 b1v = *(const bf16x8*)(bp + 32);
      bf16x8 b2v = *(const bf16x8*)(bp + 64);
      float bias = (c < DHID) ? b2[c] : 0.f;
      float mx0 = 0.f, sm0 = 0.f, mx1 = 0.f, sm1 = 0.f;
      float vv[4][4];
      #pragma unroll
      for (int rg = 0; rg < 4; rg++) {
        f32x4 a_ = {0.f, 0.f, 0.f, 0.f};
        a_ = __builtin_amdgcn_mfma_f32_16x16x32_bf16(afr[rg][0], b0v, a_, 0, 0, 0);
        a_ = __builtin_amdgcn_mfma_f32_16x16x32_bf16(afr[rg][1], b1v, a_, 0, 0, 0);
        a_ = __builtin_amdgcn_mfma_f32_16x16x32_bf16(afr[rg][2], b2v, a_, 0, 0, 0);
        #pragma unroll
        for (int j = 0; j < 4; j++) {
          float v = fmaxf(a_[j] + bias, 0.f);
          vv[rg][j] = v;
          if (grow[rg][j] == g0) { mx0 = fmaxf(mx0, v); sm0 += v; }
          if (grow[rg][j] == g1) { mx1 = fmaxf(mx1, v); sm1 += v; }
        }
      }
      mx0 = fmaxf(mx0, __shfl_xor(mx0, 16)); sm0 += __shfl_xor(sm0, 16);
      mx0 = fmaxf(mx0, __shfl_xor(mx0, 32)); sm0 += __shfl_xor(sm0, 32);
      mx1 = fmaxf(mx1, __shfl_xor(mx1, 16)); sm1 += __shfl_xor(sm1, 16);
      mx1 = fmaxf(mx1, __shfl_xor(mx1, 32)); sm1 += __shfl_xor(sm1, 32);
      if (hi == 0 && c < DHID) {
        pm[(size_t)b * DHID + c] = make_float2(mx0, sm0);
        pm1[(size_t)b * DHID + c] = make_float2(mx1, sm1);
      }
      if (g1 - g0 >= 2) {
        for (int g = g0 + 1; g < g1; g++) {
          float mx = 0.f, sm = 0.f;
          #pragma unroll
          for (int rg = 0; rg < 4; rg++)
            #pragma unroll
            for (int j = 0; j < 4; j++)
              if (grow[rg][j] == g) { mx = fmaxf(mx, vv[rg][j]); sm += vv[rg][j]; }
          mx = fmaxf(mx, __shfl_xor(mx, 16)); sm += __shfl_xor(sm, 16);
          mx = fmaxf(mx, __shfl_xor(mx, 32)); sm += __shfl_xor(sm, 32);
          if (hi == 0 && c < DHID) {
            atomicMax(&maxb[g * DHID + c], __float_as_int(mx));
            atomicAdd(&sump[g * DHID + c], sm);
          }
        }
      }
    }
  }
  if (t == 0 && half == 0) { blkg[b * 2] = g0; blkg[b * 2 + 1] = g1; }
}

// ---------------- pooling stage 2: merge partials, emit z as hi/lo bf16 [128][KP1] --------
__global__ __launch_bounds__(256) void k_pool2(const float2* __restrict__ pm, const float2* __restrict__ pm1,
                                               const int* __restrict__ blkg, const int* __restrict__ cnt,
                                               const int* __restrict__ maxb, const float* __restrict__ sump,
                                               unsigned short* __restrict__ zh, unsigned short* __restrict__ zl) {
  __shared__ int sstart[NGRAPH];
  int g = blockIdx.x, t = threadIdx.x;
  if (t == 0) {
    int s = 0;
    for (int i = 0; i < NGRAPH; i++) { sstart[i] = s; s += cnt[i]; }
  }
  __syncthreads();
  int c0 = cnt[g];
  int ns = sstart[g], ne = ns + c0;
  int b0 = ns / 64, b1 = (c0 > 0) ? (ne - 1) / 64 : b0 - 1;
  for (int c = t; c < DHID; c += 256) {
    float mx = __int_as_float(maxb[g * DHID + c]);
    float sm = sump[g * DHID + c];
    for (int b = b0; b <= b1; b++) {
      int gg0 = blkg[2 * b], gg1 = blkg[2 * b + 1];
      if (gg0 == g)      { float2 p = pm[(size_t)b * DHID + c];  mx = fmaxf(mx, p.x); sm += p.y; }
      else if (gg1 == g) { float2 p = pm1[(size_t)b * DHID + c]; mx = fmaxf(mx, p.x); sm += p.y; }
    }
    float vmax = (c0 > 0) ? mx : 0.f;
    float vmean = sm / (float)max(c0, 1);
    unsigned short hm = f2bf(vmax);
    zh[g * KP1 + c] = hm;
    zl[g * KP1 + c] = f2bf(vmax - bf2f(hm));
    unsigned short he = f2bf(vmean);
    zh[g * KP1 + DHID + c] = he;
    zl[g * KP1 + DHID + c] = f2bf(vmean - bf2f(he));
  }
  if (t < KP1 - 2 * DHID) {
    zh[g * KP1 + 2 * DHID + t] = 0;
    zl[g * KP1 + 2 * DHID + t] = 0;
  }
}

// ---------------- MLP1: z1 = relu(z @ Wg1 + bg1), split-bf16 MFMA, hi/lo out ----------------
__global__ __launch_bounds__(256) void k_mlp1m(const unsigned short* __restrict__ zh, const unsigned short* __restrict__ zl,
                                               const unsigned short* __restrict__ wh, const unsigned short* __restrict__ wl,
                                               const float* __restrict__ bg,
                                               unsigned short* __restrict__ z1h, unsigned short* __restrict__ z1l) {
  int t = threadIdx.x, w = t >> 6, l = t & 63;
  int lr = l & 15, hi = l >> 4, lk = hi * 8;
  int b = blockIdx.x;
  int n0 = (b >> 1) * 16;
  int m0 = (b & 1) * 64 + w * 16;
  const unsigned short* za = &zh[(size_t)(m0 + lr) * KP1 + lk];
  const unsigned short* zb = &zl[(size_t)(m0 + lr) * KP1 + lk];
  const unsigned short* wa = &wh[(size_t)(n0 + lr) * KP1 + lk];
  const unsigned short* wb = &wl[(size_t)(n0 + lr) * KP1 + lk];
  f32x4 acc = {0.f, 0.f, 0.f, 0.f};
  for (int ks = 0; ks < KP1 / 32; ks++) {
    bf16x8 ah = *(const bf16x8*)(za + ks * 32);
    bf16x8 al = *(const bf16x8*)(zb + ks * 32);
    bf16x8 bh = *(const bf16x8*)(wa + ks * 32);
    bf16x8 bl = *(const bf16x8*)(wb + ks * 32);
    acc = __builtin_amdgcn_mfma_f32_16x16x32_bf16(ah, bh, acc, 0, 0, 0);
    acc = __builtin_amdgcn_mfma_f32_16x16x32_bf16(al, bh, acc, 0, 0, 0);
    acc = __builtin_amdgcn_mfma_f32_16x16x32_bf16(ah, bl, acc, 0, 0, 0);
  }
  int col = n0 + lr;
  float bias = bg[col];
  #pragma unroll
  for (int j = 0; j < 4; j++) {
    int row = m0 + hi * 4 + j;
    float v = fmaxf(acc[j] + bias, 0.f);
    unsigned short h = f2bf(v);
    z1h[row * DF1 + col] = h;
    z1l[row * DF1 + col] = f2bf(v - bf2f(h));
  }
}

// ---------------- MLP2: out = z1 @ Wg2 + bg2, split-bf16 MFMA, f32 out ----------------
__global__ __launch_bounds__(256) void k_mlp2m(const unsigned short* __restrict__ z1h, const unsigned short* __restrict__ z1l,
                                               const unsigned short* __restrict__ wh, const unsigned short* __restrict__ wl,
                                               const float* __restrict__ bg, float* __restrict__ out) {
  int t = threadIdx.x, w = t >> 6, l = t & 63;
  int lr = l & 15, hi = l >> 4, lk = hi * 8;
  int b = blockIdx.x;
  int n0 = (b >> 1) * 16;
  int m0 = (b & 1) * 64 + w * 16;
  const unsigned short* za = &z1h[(size_t)(m0 + lr) * DF1 + lk];
  const unsigned short* zb = &z1l[(size_t)(m0 + lr) * DF1 + lk];
  const unsigned short* wa = &wh[(size_t)(n0 + lr) * DF1 + lk];
  const unsigned short* wb = &wl[(size_t)(n0 + lr) * DF1 + lk];
  f32x4 acc = {0.f, 0.f, 0.f, 0.f};
  for (int ks = 0; ks < DF1 / 32; ks++) {
    bf16x8 ah = *(const bf16x8*)(za + ks * 32);
    bf16x8 al = *(const bf16x8*)(zb + ks * 32);
    bf16x8 bh = *(const bf16x8*)(wa + ks * 32);
    bf16x8 bl = *(const bf16x8*)(wb + ks * 32);
    acc = __builtin_amdgcn_mfma_f32_16x16x32_bf16(ah, bh, acc, 0, 0, 0);
    acc = __builtin_amdgcn_mfma_f32_16x16x32_bf16(al, bh, acc, 0, 0, 0);
    acc = __builtin_amdgcn_mfma_f32_16x16x32_bf16(ah, bl, acc, 0, 0, 0);
  }
  int col = n0 + lr;
  float bias = bg[col];
  #pragma unroll
  for (int j = 0; j < 4; j++) {
    int row = m0 + hi * 4 + j;
    out[row * DOUTC + col] = acc[j] + bias;
  }
}

// ---------------- launch ----------------
static constexpr size_t AL(size_t x) { return (x + 255) & ~(size_t)255; }

extern "C" void kernel_launch(void* const* d_in, const int* in_sizes, int n_in,
                              void* d_out, int out_size, void* d_ws, size_t ws_size,
                              hipStream_t stream) {
  const float* x   = (const float*)d_in[0];
  const int*  edge = (const int*)d_in[1];
  const int*  batch= (const int*)d_in[2];
  const float* W1  = (const float*)d_in[3];
  const float* b1  = (const float*)d_in[4];
  const float* W2  = (const float*)d_in[5];
  const float* b2  = (const float*)d_in[6];
  const float* Wg1 = (const float*)d_in[7];
  const float* bg1 = (const float*)d_in[8];
  const float* Wg2 = (const float*)d_in[9];
  const float* bg2 = (const float*)d_in[10];
  float* out = (float*)d_out;
  const int* src = edge;
  const int* dst = edge + N_EDGESC;

  size_t o = 0;
  size_t OFF_AGG = o;  o += AL((size_t)N_NODES * DIN * 4);    // pooling partials scratch
  size_t OFF_AGH = o;  o += AL((size_t)N_NODES * XSTR * 2);   // aggh hi bf16
  size_t OFF_AGL = o;  o += AL((size_t)N_NODES * XSTR * 2);   // aggl lo bf16
  size_t OFF_H1  = o;  o += AL((size_t)N_NODES * XSTR * 2);   // h1b bf16, stride 96
  size_t OFF_AGB = o;  o += AL((size_t)N_NODES * XSTR * 2);   // xb then aggb (both stride 96)
  size_t OFF_CSR = o;  o += AL((size_t)N_EDGESC * 4);
  size_t OFF_REC = o;  o += AL((size_t)N_EDGESC * 4);
  size_t OFF_W2T = o;  o += AL((size_t)896 * 96 * 2);
  size_t OFF_W1H = o;  o += AL((size_t)96 * 96 * 2);
  size_t OFF_W1L = o;  o += AL((size_t)96 * 96 * 2);
  size_t OFF_G1H = o;  o += AL((size_t)DF1 * KP1 * 2);
  size_t OFF_G1L = o;  o += AL((size_t)DF1 * KP1 * 2);
  size_t OFF_G2H = o;  o += AL((size_t)DOUTC * DF1 * 2);
  size_t OFF_G2L = o;  o += AL((size_t)DOUTC * DF1 * 2);
  size_t OFF_ZH  = o;  o += AL((size_t)NGRAPH * KP1 * 2);
  size_t OFF_ZL  = o;  o += AL((size_t)NGRAPH * KP1 * 2);
  size_t OFF_Z1H = o;  o += AL((size_t)NGRAPH * DF1 * 2);
  size_t OFF_Z1L = o;  o += AL((size_t)NGRAPH * DF1 * 2);
  size_t OFF_RP  = o;  o += AL((size_t)(N_NODES + 1) * 4);
  size_t OFF_BOF = o;  o += AL((NBUCK + 1) * 4);
  size_t OFF_BCU = o;  o += AL(NBUCK * 4);
  size_t OFF_BC  = o;  o += AL(NBUCK * 4);                    // zero region starts here
  size_t OFF_MAX = o;  o += AL((size_t)NGRAPH * DHID * 4);
  size_t OFF_SUM = o;  o += AL((size_t)NGRAPH * DHID * 4);
  size_t OFF_CNT = o;  o += AL(NGRAPH * 4);
  size_t TOTAL = o;
  size_t ZERO0 = OFF_BC, ZEROB = TOTAL - OFF_BC;
  if (ws_size < TOTAL) return;

  size_t PB = AL((size_t)PBLK3 * DHID * 8);
  size_t OFF_PM  = OFF_AGG;                 // pm aliases agg region + aggh (33.6MB + 19.2MB > 21MB needed)
  size_t OFF_PM1 = OFF_AGG + PB;
  size_t OFF_BLG = OFF_AGG + 2 * PB;

  char* ws = (char*)d_ws;
  unsigned short* aggh = (unsigned short*)(ws + OFF_AGH);
  unsigned short* aggl = (unsigned short*)(ws + OFF_AGL);
  unsigned short* h1b = (unsigned short*)(ws + OFF_H1);
  unsigned short* aggb = (unsigned short*)(ws + OFF_AGB);
  unsigned short* xb   = (unsigned short*)(ws + OFF_AGB);   // alias: xb dead before aggb written
  int* csr   = (int*)(ws + OFF_CSR);
  unsigned int* rec = (unsigned int*)(ws + OFF_REC);
  unsigned short* w2t = (unsigned short*)(ws + OFF_W2T);
  unsigned short* w1h = (unsigned short*)(ws + OFF_W1H);
  unsigned short* w1l = (unsigned short*)(ws + OFF_W1L);
  unsigned short* g1h = (unsigned short*)(ws + OFF_G1H);
  unsigned short* g1l = (unsigned short*)(ws + OFF_G1L);
  unsigned short* g2h = (unsigned short*)(ws + OFF_G2H);
  unsigned short* g2l = (unsigned short*)(ws + OFF_G2L);
  unsigned short* zh  = (unsigned short*)(ws + OFF_ZH);
  unsigned short* zl  = (unsigned short*)(ws + OFF_ZL);
  unsigned short* z1h = (unsigned short*)(ws + OFF_Z1H);
  unsigned short* z1l = (unsigned short*)(ws + OFF_Z1L);
  int* rowptr = (int*)(ws + OFF_RP);
  int* boff  = (int*)(ws + OFF_BOF);
  int* bcur  = (int*)(ws + OFF_BCU);
  int* bcnt  = (int*)(ws + OFF_BC);
  int* maxb  = (int*)(ws + OFF_MAX);
  float* sump= (float*)(ws + OFF_SUM);
  int* cnt   = (int*)(ws + OFF_CNT);
  float2* pm  = (float2*)(ws + OFF_PM);
  float2* pm1 = (float2*)(ws + OFF_PM1);
  int* blkg  = (int*)(ws + OFF_BLG);

  hipMemsetAsync(ws + ZERO0, 0, ZEROB, stream);

  k_prep<<<PREP_B, 256, 0, stream>>>(x, xb, W2, w2t, W1, w1h, w1l, batch, cnt,
                                     Wg1, g1h, g1l, Wg2, g2h, g2l);

  int nbb = (N_EDGESC + EPB - 1) / EPB;   // 391
  k_bhist<<<nbb, 256, 0, stream>>>(dst, bcnt);
  k_bscan<<<1, 512, 0, stream>>>(bcnt, boff, bcur);
  k_bfill<<<nbb, 256, 0, stream>>>(src, dst, bcur, rec);
  k_bsort<<<NBUCK, 256, 0, stream>>>(rec, boff, rowptr, csr);

  k_agg1c<<<(N_NODES + 11) / 12, 256, 0, stream>>>(xb, rowptr, csr, aggh, aggl);
  k_conv1m2<<<PBLK3, 256, 0, stream>>>(aggh, aggl, w1h, w1l, b1, h1b);
  k_agg2<<<(N_NODES + 11) / 12, 256, 0, stream>>>(h1b, rowptr, csr, aggb);
  k_conv2pool4<<<2 * PBLK3, 256, 0, stream>>>(aggb, w2t, b2, batch, pm, pm1, blkg, maxb, sump);
  k_pool2<<<NGRAPH, 256, 0, stream>>>(pm, pm1, blkg, cnt, maxb, sump, zh, zl);

  k_mlp1m<<<(DF1 / 16) * 2, 256, 0, stream>>>(zh, zl, g1h, g1l, bg1, z1h, z1l);
  k_mlp2m<<<(DOUTC / 16) * 2, 256, 0, stream>>>(z1h, z1l, g2h, g2l, bg2, out);
}

// Round 14
// 247.154 us; speedup vs baseline: 1.0313x; 1.0313x over previous
//
#include <hip/hip_runtime.h>

#define N_NODES 100000
#define N_EDGESC 800000
#define NGRAPH 128
#define DIN 84
#define DHID 840
#define DF1 1024
#define DOUTC 384
#define PBLK3 1563  // ceil(N_NODES/64) row-tiles
#define KP1 1696    // 2*DHID padded to x32
#define NBUCK 391   // ceil(N_NODES/256)
#define EPB 2048    // edges per bucketing block (grid 391)
#define XSTR 96     // padded row stride (192B = 3 aligned lines)

// k_prep block ranges
#define XBF_B 9375  // ceil(N_NODES*24/256)
#define W2T_B 336   // ceil(896*96/256)
#define W1T_B 36    // ceil(96*96/256)
#define CNT_B 49    // ceil(N_NODES/2048)
#define G1_B  1696  // (KP1/32)*(DF1/32)
#define G2_B  384   // (DF1/32)*(DOUTC/32)
#define PREP_B (XBF_B + W2T_B + W1T_B + CNT_B + G1_B + G2_B)

typedef __attribute__((ext_vector_type(4))) float f32x4;
typedef __attribute__((ext_vector_type(8))) short bf16x8;

__device__ __forceinline__ unsigned short f2bf(float f) {
  union { float f; unsigned int u; } v; v.f = f;
  unsigned int r = v.u + 0x7FFFu + ((v.u >> 16) & 1u);
  return (unsigned short)(r >> 16);
}
__device__ __forceinline__ float bf2f(unsigned short h) {
  union { unsigned int u; float f; } v; v.u = ((unsigned int)h) << 16;
  return v.f;
}
__device__ __forceinline__ f32x4 bfq(uint2 p) {
  f32x4 r;
  r.x = bf2f((unsigned short)(p.x & 0xffff)); r.y = bf2f((unsigned short)(p.x >> 16));
  r.z = bf2f((unsigned short)(p.y & 0xffff)); r.w = bf2f((unsigned short)(p.y >> 16));
  return r;
}

// ---------------- bucketed CSR build ----------------
__global__ __launch_bounds__(256) void k_bhist(const int* __restrict__ dst, int* __restrict__ bcnt) {
  __shared__ int h[NBUCK];
  int t = threadIdx.x;
  for (int i = t; i < NBUCK; i += 256) h[i] = 0;
  __syncthreads();
  int base = blockIdx.x * EPB;
  int e1 = min(base + EPB, N_EDGESC);
  for (int e = base + t; e < e1; e += 256)
    atomicAdd(&h[dst[e] >> 8], 1);
  __syncthreads();
  for (int i = t; i < NBUCK; i += 256) if (h[i]) atomicAdd(&bcnt[i], h[i]);
}

__global__ __launch_bounds__(512) void k_bscan(const int* __restrict__ bcnt, int* __restrict__ boff,
                                               int* __restrict__ bcur) {
  __shared__ int sd[512];
  int t = threadIdx.x;
  int v = (t < NBUCK) ? bcnt[t] : 0;
  sd[t] = v; __syncthreads();
  for (int off = 1; off < 512; off <<= 1) {
    int add = (t >= off) ? sd[t - off] : 0;
    __syncthreads();
    sd[t] += add;
    __syncthreads();
  }
  if (t <= NBUCK) {
    boff[t] = sd[t] - v;
    if (t < NBUCK) bcur[t] = sd[t] - v;
  }
}

__global__ __launch_bounds__(256) void k_bfill(const int* __restrict__ src, const int* __restrict__ dst,
                                               int* __restrict__ bcur, unsigned int* __restrict__ rec) {
  __shared__ int hcnt[NBUCK];
  __shared__ int hbase[NBUCK];
  int t = threadIdx.x;
  int e0 = blockIdx.x * EPB;
  int e1 = min(e0 + EPB, N_EDGESC);
  for (int i = t; i < NBUCK; i += 256) hcnt[i] = 0;
  __syncthreads();
  for (int e = e0 + t; e < e1; e += 256)
    atomicAdd(&hcnt[dst[e] >> 8], 1);
  __syncthreads();
  for (int i = t; i < NBUCK; i += 256) {
    int c = hcnt[i];
    hbase[i] = c ? atomicAdd(&bcur[i], c) : 0;
  }
  __syncthreads();
  for (int i = t; i < NBUCK; i += 256) hcnt[i] = 0;
  __syncthreads();
  for (int e = e0 + t; e < e1; e += 256) {
    int d = dst[e];
    int b = d >> 8;
    int r = atomicAdd(&hcnt[b], 1);
    rec[hbase[b] + r] = ((unsigned int)(d & 255) << 24) | (unsigned int)src[e];
  }
}

__global__ __launch_bounds__(256) void k_bsort(const unsigned int* __restrict__ rec, const int* __restrict__ boff,
                                               int* __restrict__ rowptr, int* __restrict__ csr) {
  __shared__ int lcnt[256];
  __shared__ int lcur[256];
  int b = blockIdx.x, t = threadIdx.x;
  int e0 = boff[b], e1 = boff[b + 1];
  lcnt[t] = 0;
  __syncthreads();
  for (int i = e0 + t; i < e1; i += 256) atomicAdd(&lcnt[rec[i] >> 24], 1);
  __syncthreads();
  int v = lcnt[t];
  for (int off = 1; off < 256; off <<= 1) {
    int add = (t >= off) ? lcnt[t - off] : 0;
    __syncthreads();
    lcnt[t] += add;
    __syncthreads();
  }
  int excl = lcnt[t] - v;
  int node = b * 256 + t;
  if (node < N_NODES) rowptr[node] = e0 + excl;
  lcur[t] = e0 + excl;
  if (b == NBUCK - 1 && t == 0) rowptr[N_NODES] = N_EDGESC;
  __syncthreads();
  for (int i = e0 + t; i < e1; i += 256) {
    unsigned int r = rec[i];
    int d = r >> 24;
    int pos = atomicAdd(&lcur[d], 1);
    csr[pos] = (int)(r & 0xFFFFFFu);
  }
}

// ---------------- fused prep: xbf | w2t | w1t | counts | wsplit(Wg1) | wsplit(Wg2) --------
__global__ __launch_bounds__(256) void k_prep(const float* __restrict__ x, unsigned short* __restrict__ xb,
                                              const float* __restrict__ W2, unsigned short* __restrict__ w2t,
                                              const float* __restrict__ W1, unsigned short* __restrict__ w1h,
                                              unsigned short* __restrict__ w1l,
                                              const int* __restrict__ batch, int* __restrict__ cnt,
                                              const float* __restrict__ Wg1, unsigned short* __restrict__ g1h,
                                              unsigned short* __restrict__ g1l,
                                              const float* __restrict__ Wg2, unsigned short* __restrict__ g2h,
                                              unsigned short* __restrict__ g2l) {
  __shared__ float tile[32][33];
  __shared__ int h[NGRAPH];
  int b = blockIdx.x, t = threadIdx.x;

  if (b < XBF_B) {
    int idx = b * 256 + t;
    if (idx >= N_NODES * 24) return;
    int r = idx / 24, c = idx - r * 24;
    uint2 p = {0u, 0u};
    if (c < 21) {
      f32x4 v = *(const f32x4*)&x[r * DIN + c * 4];
      p.x = (unsigned int)f2bf(v.x) | ((unsigned int)f2bf(v.y) << 16);
      p.y = (unsigned int)f2bf(v.z) | ((unsigned int)f2bf(v.w) << 16);
    }
    *(uint2*)&xb[r * XSTR + c * 4] = p;
    return;
  }
  b -= XBF_B;
  if (b < W2T_B) {
    int idx = b * 256 + t;
    if (idx >= 896 * 96) return;
    int n = idx / 96, k = idx % 96;
    float v = (n < DHID && k < DIN) ? W2[k * DHID + n] : 0.f;
    w2t[idx] = f2bf(v);
    return;
  }
  b -= W2T_B;
  if (b < W1T_B) {
    int idx = b * 256 + t;
    if (idx >= 96 * 96) return;
    int n = idx / 96, k = idx % 96;
    float v = (n < DIN && k < DIN) ? W1[k * DIN + n] : 0.f;
    unsigned short hh = f2bf(v);
    w1h[idx] = hh;
    w1l[idx] = f2bf(v - bf2f(hh));
    return;
  }
  b -= W1T_B;
  if (b < CNT_B) {
    if (t < NGRAPH) h[t] = 0;
    __syncthreads();
    int base = b * 2048;
    for (int j = 0; j < 8; j++) {
      int i = base + j * 256 + t;
      if (i < N_NODES) atomicAdd(&h[batch[i]], 1);
    }
    __syncthreads();
    if (t < NGRAPH && h[t] > 0) atomicAdd(&cnt[t], h[t]);
    return;
  }
  b -= CNT_B;
  const float* W; unsigned short *wh, *wl; int K, KPAD, N, vb;
  if (b < G1_B) { W = Wg1; wh = g1h; wl = g1l; K = 2 * DHID; KPAD = KP1; N = DF1; vb = b; }
  else          { W = Wg2; wh = g2h; wl = g2l; K = DF1; KPAD = DF1; N = DOUTC; vb = b - G1_B; }
  int kt = vb % (KPAD / 32), nt2 = vb / (KPAD / 32);
  int k0 = kt * 32, n0 = nt2 * 32;
  int r = t >> 3, c4 = (t & 7) * 4;
  int k = k0 + r;
  f32x4 v = {0.f, 0.f, 0.f, 0.f};
  if (k < K) v = *(const f32x4*)&W[(size_t)k * N + n0 + c4];
  tile[r][c4 + 0] = v.x; tile[r][c4 + 1] = v.y; tile[r][c4 + 2] = v.z; tile[r][c4 + 3] = v.w;
  __syncthreads();
  int n = t >> 3;
  float f0 = tile[c4 + 0][n], f1 = tile[c4 + 1][n], f2 = tile[c4 + 2][n], f3 = tile[c4 + 3][n];
  unsigned short h0 = f2bf(f0), h1_ = f2bf(f1), h2_ = f2bf(f2), h3_ = f2bf(f3);
  uint2 ph, pl;
  ph.x = (unsigned int)h0 | ((unsigned int)h1_ << 16);
  ph.y = (unsigned int)h2_ | ((unsigned int)h3_ << 16);
  pl.x = (unsigned int)f2bf(f0 - bf2f(h0)) | ((unsigned int)f2bf(f1 - bf2f(h1_)) << 16);
  pl.y = (unsigned int)f2bf(f2 - bf2f(h2_)) | ((unsigned int)f2bf(f3 - bf2f(h3_)) << 16);
  *(uint2*)&wh[(size_t)(n0 + n) * KPAD + k0 + c4] = ph;
  *(uint2*)&wl[(size_t)(n0 + n) * KPAD + k0 + c4] = pl;
}

// ---------------- agg1c: bf16 gather (stride 96) -> bf16 out (stride 96, zero-pad) -------
// 3 nodes per 64-lane wave, 12 nodes/block. Output rounded to plain bf16 (same rounding
// agg2 applies); W1 stays split hi/lo so conv1 keeps f32-accurate weights.
__global__ __launch_bounds__(256) void k_agg1c(const unsigned short* __restrict__ xb,
                                               const int* __restrict__ rowptr,
                                               const int* __restrict__ csr,
                                               unsigned short* __restrict__ aggh) {
  int t = threadIdx.x;
  int wv = t >> 6, l = t & 63;
  int grp = (l >= 42) ? 2 : (l >= 21 ? 1 : 0);
  int li = l - grp * 21;
  int node = blockIdx.x * 12 + wv * 3 + grp;
  bool act = (li < 21) && (node < N_NODES);
  if (l == 63) {   // zero pads for this wave's 3 rows
    uint2 z = {0u, 0u};
    for (int g = 0; g < 3; g++) {
      int nd = blockIdx.x * 12 + wv * 3 + g;
      if (nd < N_NODES) {
        *(uint2*)&aggh[nd * XSTR + 84] = z; *(uint2*)&aggh[nd * XSTR + 88] = z; *(uint2*)&aggh[nd * XSTR + 92] = z;
      }
    }
  }
  int nclamp = min(node, N_NODES - 1);
  int r0 = rowptr[nclamp];
  int r1 = act ? rowptr[nclamp + 1] : r0;
  f32x4 a = {0.f, 0.f, 0.f, 0.f};
  if (act) a = bfq(*(const uint2*)&xb[nclamp * XSTR + li * 4]);
  int e = r0;
  for (; e + 8 <= r1; e += 8) {
    int s0 = csr[e], s1 = csr[e + 1], s2 = csr[e + 2], s3 = csr[e + 3];
    int s4 = csr[e + 4], s5 = csr[e + 5], s6 = csr[e + 6], s7 = csr[e + 7];
    uint2 q0 = *(const uint2*)&xb[s0 * XSTR + li * 4];
    uint2 q1 = *(const uint2*)&xb[s1 * XSTR + li * 4];
    uint2 q2 = *(const uint2*)&xb[s2 * XSTR + li * 4];
    uint2 q3 = *(const uint2*)&xb[s3 * XSTR + li * 4];
    uint2 q4 = *(const uint2*)&xb[s4 * XSTR + li * 4];
    uint2 q5 = *(const uint2*)&xb[s5 * XSTR + li * 4];
    uint2 q6 = *(const uint2*)&xb[s6 * XSTR + li * 4];
    uint2 q7 = *(const uint2*)&xb[s7 * XSTR + li * 4];
    a += ((bfq(q0) + bfq(q1)) + (bfq(q2) + bfq(q3))) + ((bfq(q4) + bfq(q5)) + (bfq(q6) + bfq(q7)));
  }
  for (; e + 4 <= r1; e += 4) {
    int s0 = csr[e], s1 = csr[e + 1], s2 = csr[e + 2], s3 = csr[e + 3];
    uint2 q0 = *(const uint2*)&xb[s0 * XSTR + li * 4];
    uint2 q1 = *(const uint2*)&xb[s1 * XSTR + li * 4];
    uint2 q2 = *(const uint2*)&xb[s2 * XSTR + li * 4];
    uint2 q3 = *(const uint2*)&xb[s3 * XSTR + li * 4];
    a += (bfq(q0) + bfq(q1)) + (bfq(q2) + bfq(q3));
  }
  for (; e < r1; e++) {
    int s = csr[e];
    a += bfq(*(const uint2*)&xb[s * XSTR + li * 4]);
  }
  if (act) {
    uint2 p;
    p.x = (unsigned int)f2bf(a.x) | ((unsigned int)f2bf(a.y) << 16);
    p.y = (unsigned int)f2bf(a.z) | ((unsigned int)f2bf(a.w) << 16);
    *(uint2*)&aggh[node * XSTR + li * 4] = p;
  }
}

// ---------------- conv1m2: MFMA from global bf16 A (no LDS), split W1, h1b bf16 out -------
__global__ __launch_bounds__(256) void k_conv1m2(const unsigned short* __restrict__ aggh,
                                                 const unsigned short* __restrict__ w1h,
                                                 const unsigned short* __restrict__ w1l,
                                                 const float* __restrict__ b1,
                                                 unsigned short* __restrict__ h1b) {
  int t = threadIdx.x;
  int m0 = blockIdx.x * 64;
  int wv = t >> 6, l = t & 63;
  int lr = l & 15, lk = (l >> 4) * 8;
  int row = m0 + wv * 16 + lr;
  bool inb = row < N_NODES;
  bf16x8 ah[3];
  #pragma unroll
  for (int kk = 0; kk < 3; kk++) {
    bf16x8 vh = {0, 0, 0, 0, 0, 0, 0, 0};
    if (inb) vh = *(const bf16x8*)&aggh[(size_t)row * XSTR + lk + kk * 32];
    ah[kk] = vh;
  }
  #pragma unroll
  for (int nt = 0; nt < 6; nt++) {
    f32x4 acc = {0.f, 0.f, 0.f, 0.f};
    #pragma unroll
    for (int kk = 0; kk < 3; kk++) {
      bf16x8 bh = *(const bf16x8*)&w1h[(nt * 16 + lr) * 96 + lk + kk * 32];
      bf16x8 bl = *(const bf16x8*)&w1l[(nt * 16 + lr) * 96 + lk + kk * 32];
      acc = __builtin_amdgcn_mfma_f32_16x16x32_bf16(ah[kk], bh, acc, 0, 0, 0);
      acc = __builtin_amdgcn_mfma_f32_16x16x32_bf16(ah[kk], bl, acc, 0, 0, 0);
    }
    int col = nt * 16 + lr;
    if (col < DIN) {
      float bias = b1[col];
      int rbase = m0 + wv * 16 + (l >> 4) * 4;
      #pragma unroll
      for (int j = 0; j < 4; j++) {
        if (rbase + j < N_NODES)
          h1b[(rbase + j) * XSTR + col] = f2bf(fmaxf(acc[j] + bias, 0.f));
      }
    }
  }
}

// ---------------- agg2: bf16 in (stride 96), bf16 out cols 0..83 (stride 96) -------------
__global__ __launch_bounds__(256) void k_agg2(const unsigned short* __restrict__ h1b, const int* __restrict__ rowptr,
                                              const int* __restrict__ csr, unsigned short* __restrict__ out) {
  int t = threadIdx.x;
  int wv = t >> 6, l = t & 63;
  int grp = (l >= 42) ? 2 : (l >= 21 ? 1 : 0);
  int li = l - grp * 21;
  int node = blockIdx.x * 12 + wv * 3 + grp;
  bool act = (li < 21) && (node < N_NODES);
  int nclamp = min(node, N_NODES - 1);
  int r0 = rowptr[nclamp];
  int r1 = act ? rowptr[nclamp + 1] : r0;
  f32x4 a = {0.f, 0.f, 0.f, 0.f};
  if (act) a = bfq(*(const uint2*)&h1b[nclamp * XSTR + li * 4]);
  int e = r0;
  for (; e + 8 <= r1; e += 8) {
    int s0 = csr[e], s1 = csr[e + 1], s2 = csr[e + 2], s3 = csr[e + 3];
    int s4 = csr[e + 4], s5 = csr[e + 5], s6 = csr[e + 6], s7 = csr[e + 7];
    uint2 q0 = *(const uint2*)&h1b[s0 * XSTR + li * 4];
    uint2 q1 = *(const uint2*)&h1b[s1 * XSTR + li * 4];
    uint2 q2 = *(const uint2*)&h1b[s2 * XSTR + li * 4];
    uint2 q3 = *(const uint2*)&h1b[s3 * XSTR + li * 4];
    uint2 q4 = *(const uint2*)&h1b[s4 * XSTR + li * 4];
    uint2 q5 = *(const uint2*)&h1b[s5 * XSTR + li * 4];
    uint2 q6 = *(const uint2*)&h1b[s6 * XSTR + li * 4];
    uint2 q7 = *(const uint2*)&h1b[s7 * XSTR + li * 4];
    a += ((bfq(q0) + bfq(q1)) + (bfq(q2) + bfq(q3))) + ((bfq(q4) + bfq(q5)) + (bfq(q6) + bfq(q7)));
  }
  for (; e + 4 <= r1; e += 4) {
    int s0 = csr[e], s1 = csr[e + 1], s2 = csr[e + 2], s3 = csr[e + 3];
    uint2 q0 = *(const uint2*)&h1b[s0 * XSTR + li * 4];
    uint2 q1 = *(const uint2*)&h1b[s1 * XSTR + li * 4];
    uint2 q2 = *(const uint2*)&h1b[s2 * XSTR + li * 4];
    uint2 q3 = *(const uint2*)&h1b[s3 * XSTR + li * 4];
    a += (bfq(q0) + bfq(q1)) + (bfq(q2) + bfq(q3));
  }
  for (; e < r1; e++) {
    int s = csr[e];
    a += bfq(*(const uint2*)&h1b[s * XSTR + li * 4]);
  }
  if (act) {
    uint2 p;
    p.x = (unsigned int)f2bf(a.x) | ((unsigned int)f2bf(a.y) << 16);
    p.y = (unsigned int)f2bf(a.z) | ((unsigned int)f2bf(a.w) << 16);
    *(uint2*)&out[node * XSTR + li * 4] = p;
  }
}

// ---------------- conv2 + pooling stage 1: 64-row tiles x 2 column-halves ----------------
__global__ __launch_bounds__(256) void k_conv2pool4(const unsigned short* __restrict__ aggb,
                                                    const unsigned short* __restrict__ w2t,
                                                    const float* __restrict__ b2,
                                                    const int* __restrict__ batch,
                                                    float2* __restrict__ pm, float2* __restrict__ pm1,
                                                    int* __restrict__ blkg,
                                                    int* __restrict__ maxb, float* __restrict__ sump) {
  constexpr int LDA = 104;
  __shared__ __align__(16) unsigned short At[64 * LDA];
  int t = threadIdx.x;
  int w = t >> 6, l = t & 63;
  int b = blockIdx.x >> 1;
  int half = blockIdx.x & 1;
  int m0 = b * 64;
  int lr = l & 15, hi = l >> 4, lk = hi * 8;

  for (int idx = t; idx < 64 * 12; idx += 256) {
    int r = idx / 12, c = idx - r * 12;
    uint4 v = {0u, 0u, 0u, 0u};
    int row = m0 + r;
    if (row < N_NODES) v = *(const uint4*)&aggb[row * XSTR + c * 8];
    *(uint4*)&At[r * LDA + c * 8] = v;
  }
  int g0 = batch[m0];
  int g1 = batch[min(m0 + 63, N_NODES - 1)];
  bool fast = (g0 == g1) && (m0 + 63 < N_NODES);
  __syncthreads();

  bf16x8 afr[4][3];
  #pragma unroll
  for (int rg = 0; rg < 4; rg++)
    #pragma unroll
    for (int kk = 0; kk < 3; kk++)
      afr[rg][kk] = *(bf16x8*)&At[(rg * 16 + lr) * LDA + lk + kk * 32];

  int pbase = half * 28 + w * 7;

  if (fast) {
    for (int i = 0; i < 7; i++) {
      int c = (pbase + i) * 16 + lr;
      const unsigned short* bp = &w2t[c * 96 + lk];
      bf16x8 b0v = *(const bf16x8*)(bp);
      bf16x8 b1v = *(const bf16x8*)(bp + 32);
      bf16x8 b2v = *(const bf16x8*)(bp + 64);
      float bias = (c < DHID) ? b2[c] : 0.f;
      float mx = 0.f, sm = 0.f;
      #pragma unroll
      for (int rg = 0; rg < 4; rg++) {
        f32x4 a_ = {0.f, 0.f, 0.f, 0.f};
        a_ = __builtin_amdgcn_mfma_f32_16x16x32_bf16(afr[rg][0], b0v, a_, 0, 0, 0);
        a_ = __builtin_amdgcn_mfma_f32_16x16x32_bf16(afr[rg][1], b1v, a_, 0, 0, 0);
        a_ = __builtin_amdgcn_mfma_f32_16x16x32_bf16(afr[rg][2], b2v, a_, 0, 0, 0);
        float v0 = fmaxf(a_[0] + bias, 0.f);
        float v1 = fmaxf(a_[1] + bias, 0.f);
        float v2 = fmaxf(a_[2] + bias, 0.f);
        float v3 = fmaxf(a_[3] + bias, 0.f);
        mx = fmaxf(mx, fmaxf(fmaxf(v0, v1), fmaxf(v2, v3)));
        sm += (v0 + v1) + (v2 + v3);
      }
      mx = fmaxf(mx, __shfl_xor(mx, 16)); sm += __shfl_xor(sm, 16);
      mx = fmaxf(mx, __shfl_xor(mx, 32)); sm += __shfl_xor(sm, 32);
      if (hi == 0 && c < DHID) pm[(size_t)b * DHID + c] = make_float2(mx, sm);
    }
  } else {
    int grow[4][4];
    #pragma unroll
    for (int rg = 0; rg < 4; rg++)
      #pragma unroll
      for (int j = 0; j < 4; j++) {
        int row = m0 + rg * 16 + hi * 4 + j;
        grow[rg][j] = (row < N_NODES) ? batch[row] : -1;
      }
    for (int i = 0; i < 7; i++) {
      int c = (pbase + i) * 16 + lr;
      const unsigned short* bp = &w2t[c * 96 + lk];
      bf16x8 b0v = *(const bf16x8*)(bp);
      bf16x8 b1v = *(const bf16x8*)(bp + 32);
      bf16x8 b2v = *(const bf16x8*)(bp + 64);
      float bias = (c < DHID) ? b2[c] : 0.f;
      float mx0 = 0.f, sm0 = 0.f, mx1 = 0.f, sm1 = 0.f;
      float vv[4][4];
      #pragma unroll
      for (int rg = 0; rg < 4; rg++) {
        f32x4 a_ = {0.f, 0.f, 0.f, 0.f};
        a_ = __builtin_amdgcn_mfma_f32_16x16x32_bf16(afr[rg][0], b0v, a_, 0, 0, 0);
        a_ = __builtin_amdgcn_mfma_f32_16x16x32_bf16(afr[rg][1], b1v, a_, 0, 0, 0);
        a_ = __builtin_amdgcn_mfma_f32_16x16x32_bf16(afr[rg][2], b2v, a_, 0, 0, 0);
        #pragma unroll
        for (int j = 0; j < 4; j++) {
          float v = fmaxf(a_[j] + bias, 0.f);
          vv[rg][j] = v;
          if (grow[rg][j] == g0) { mx0 = fmaxf(mx0, v); sm0 += v; }
          if (grow[rg][j] == g1) { mx1 = fmaxf(mx1, v); sm1 += v; }
        }
      }
      mx0 = fmaxf(mx0, __shfl_xor(mx0, 16)); sm0 += __shfl_xor(sm0, 16);
      mx0 = fmaxf(mx0, __shfl_xor(mx0, 32)); sm0 += __shfl_xor(sm0, 32);
      mx1 = fmaxf(mx1, __shfl_xor(mx1, 16)); sm1 += __shfl_xor(sm1, 16);
      mx1 = fmaxf(mx1, __shfl_xor(mx1, 32)); sm1 += __shfl_xor(sm1, 32);
      if (hi == 0 && c < DHID) {
        pm[(size_t)b * DHID + c] = make_float2(mx0, sm0);
        pm1[(size_t)b * DHID + c] = make_float2(mx1, sm1);
      }
      if (g1 - g0 >= 2) {
        for (int g = g0 + 1; g < g1; g++) {
          float mx = 0.f, sm = 0.f;
          #pragma unroll
          for (int rg = 0; rg < 4; rg++)
            #pragma unroll
            for (int j = 0; j < 4; j++)
              if (grow[rg][j] == g) { mx = fmaxf(mx, vv[rg][j]); sm += vv[rg][j]; }
          mx = fmaxf(mx, __shfl_xor(mx, 16)); sm += __shfl_xor(sm, 16);
          mx = fmaxf(mx, __shfl_xor(mx, 32)); sm += __shfl_xor(sm, 32);
          if (hi == 0 && c < DHID) {
            atomicMax(&maxb[g * DHID + c], __float_as_int(mx));
            atomicAdd(&sump[g * DHID + c], sm);
          }
        }
      }
    }
  }
  if (t == 0 && half == 0) { blkg[b * 2] = g0; blkg[b * 2 + 1] = g1; }
}

// ---------------- pooling stage 2: merge partials, emit z as hi/lo bf16 [128][KP1] --------
__global__ __launch_bounds__(256) void k_pool2(const float2* __restrict__ pm, const float2* __restrict__ pm1,
                                               const int* __restrict__ blkg, const int* __restrict__ cnt,
                                               const int* __restrict__ maxb, const float* __restrict__ sump,
                                               unsigned short* __restrict__ zh, unsigned short* __restrict__ zl) {
  __shared__ int sstart[NGRAPH];
  int g = blockIdx.x, t = threadIdx.x;
  if (t == 0) {
    int s = 0;
    for (int i = 0; i < NGRAPH; i++) { sstart[i] = s; s += cnt[i]; }
  }
  __syncthreads();
  int c0 = cnt[g];
  int ns = sstart[g], ne = ns + c0;
  int b0 = ns / 64, b1 = (c0 > 0) ? (ne - 1) / 64 : b0 - 1;
  for (int c = t; c < DHID; c += 256) {
    float mx = __int_as_float(maxb[g * DHID + c]);
    float sm = sump[g * DHID + c];
    for (int b = b0; b <= b1; b++) {
      int gg0 = blkg[2 * b], gg1 = blkg[2 * b + 1];
      if (gg0 == g)      { float2 p = pm[(size_t)b * DHID + c];  mx = fmaxf(mx, p.x); sm += p.y; }
      else if (gg1 == g) { float2 p = pm1[(size_t)b * DHID + c]; mx = fmaxf(mx, p.x); sm += p.y; }
    }
    float vmax = (c0 > 0) ? mx : 0.f;
    float vmean = sm / (float)max(c0, 1);
    unsigned short hm = f2bf(vmax);
    zh[g * KP1 + c] = hm;
    zl[g * KP1 + c] = f2bf(vmax - bf2f(hm));
    unsigned short he = f2bf(vmean);
    zh[g * KP1 + DHID + c] = he;
    zl[g * KP1 + DHID + c] = f2bf(vmean - bf2f(he));
  }
  if (t < KP1 - 2 * DHID) {
    zh[g * KP1 + 2 * DHID + t] = 0;
    zl[g * KP1 + 2 * DHID + t] = 0;
  }
}

// ---------------- MLP1: z1 = relu(z @ Wg1 + bg1), split-bf16 MFMA, hi/lo out ----------------
__global__ __launch_bounds__(256) void k_mlp1m(const unsigned short* __restrict__ zh, const unsigned short* __restrict__ zl,
                                               const unsigned short* __restrict__ wh, const unsigned short* __restrict__ wl,
                                               const float* __restrict__ bg,
                                               unsigned short* __restrict__ z1h, unsigned short* __restrict__ z1l) {
  int t = threadIdx.x, w = t >> 6, l = t & 63;
  int lr = l & 15, hi = l >> 4, lk = hi * 8;
  int b = blockIdx.x;
  int n0 = (b >> 1) * 16;
  int m0 = (b & 1) * 64 + w * 16;
  const unsigned short* za = &zh[(size_t)(m0 + lr) * KP1 + lk];
  const unsigned short* zb = &zl[(size_t)(m0 + lr) * KP1 + lk];
  const unsigned short* wa = &wh[(size_t)(n0 + lr) * KP1 + lk];
  const unsigned short* wb = &wl[(size_t)(n0 + lr) * KP1 + lk];
  f32x4 acc = {0.f, 0.f, 0.f, 0.f};
  for (int ks = 0; ks < KP1 / 32; ks++) {
    bf16x8 ah = *(const bf16x8*)(za + ks * 32);
    bf16x8 al = *(const bf16x8*)(zb + ks * 32);
    bf16x8 bh = *(const bf16x8*)(wa + ks * 32);
    bf16x8 bl = *(const bf16x8*)(wb + ks * 32);
    acc = __builtin_amdgcn_mfma_f32_16x16x32_bf16(ah, bh, acc, 0, 0, 0);
    acc = __builtin_amdgcn_mfma_f32_16x16x32_bf16(al, bh, acc, 0, 0, 0);
    acc = __builtin_amdgcn_mfma_f32_16x16x32_bf16(ah, bl, acc, 0, 0, 0);
  }
  int col = n0 + lr;
  float bias = bg[col];
  #pragma unroll
  for (int j = 0; j < 4; j++) {
    int row = m0 + hi * 4 + j;
    float v = fmaxf(acc[j] + bias, 0.f);
    unsigned short h = f2bf(v);
    z1h[row * DF1 + col] = h;
    z1l[row * DF1 + col] = f2bf(v - bf2f(h));
  }
}

// ---------------- MLP2: out = z1 @ Wg2 + bg2, split-bf16 MFMA, f32 out ----------------
__global__ __launch_bounds__(256) void k_mlp2m(const unsigned short* __restrict__ z1h, const unsigned short* __restrict__ z1l,
                                               const unsigned short* __restrict__ wh, const unsigned short* __restrict__ wl,
                                               const float* __restrict__ bg, float* __restrict__ out) {
  int t = threadIdx.x, w = t >> 6, l = t & 63;
  int lr = l & 15, hi = l >> 4, lk = hi * 8;
  int b = blockIdx.x;
  int n0 = (b >> 1) * 16;
  int m0 = (b & 1) * 64 + w * 16;
  const unsigned short* za = &z1h[(size_t)(m0 + lr) * DF1 + lk];
  const unsigned short* zb = &z1l[(size_t)(m0 + lr) * DF1 + lk];
  const unsigned short* wa = &wh[(size_t)(n0 + lr) * DF1 + lk];
  const unsigned short* wb = &wl[(size_t)(n0 + lr) * DF1 + lk];
  f32x4 acc = {0.f, 0.f, 0.f, 0.f};
  for (int ks = 0; ks < DF1 / 32; ks++) {
    bf16x8 ah = *(const bf16x8*)(za + ks * 32);
    bf16x8 al = *(const bf16x8*)(zb + ks * 32);
    bf16x8 bh = *(const bf16x8*)(wa + ks * 32);
    bf16x8 bl = *(const bf16x8*)(wb + ks * 32);
    acc = __builtin_amdgcn_mfma_f32_16x16x32_bf16(ah, bh, acc, 0, 0, 0);
    acc = __builtin_amdgcn_mfma_f32_16x16x32_bf16(al, bh, acc, 0, 0, 0);
    acc = __builtin_amdgcn_mfma_f32_16x16x32_bf16(ah, bl, acc, 0, 0, 0);
  }
  int col = n0 + lr;
  float bias = bg[col];
  #pragma unroll
  for (int j = 0; j < 4; j++) {
    int row = m0 + hi * 4 + j;
    out[row * DOUTC + col] = acc[j] + bias;
  }
}

// ---------------- launch ----------------
static constexpr size_t AL(size_t x) { return (x + 255) & ~(size_t)255; }

extern "C" void kernel_launch(void* const* d_in, const int* in_sizes, int n_in,
                              void* d_out, int out_size, void* d_ws, size_t ws_size,
                              hipStream_t stream) {
  const float* x   = (const float*)d_in[0];
  const int*  edge = (const int*)d_in[1];
  const int*  batch= (const int*)d_in[2];
  const float* W1  = (const float*)d_in[3];
  const float* b1  = (const float*)d_in[4];
  const float* W2  = (const float*)d_in[5];
  const float* b2  = (const float*)d_in[6];
  const float* Wg1 = (const float*)d_in[7];
  const float* bg1 = (const float*)d_in[8];
  const float* Wg2 = (const float*)d_in[9];
  const float* bg2 = (const float*)d_in[10];
  float* out = (float*)d_out;
  const int* src = edge;
  const int* dst = edge + N_EDGESC;

  size_t o = 0;
  size_t OFF_AGG = o;  o += AL((size_t)N_NODES * DIN * 4);    // pooling partials scratch
  size_t OFF_AGH = o;  o += AL((size_t)N_NODES * XSTR * 2);   // aggh bf16
  size_t OFF_H1  = o;  o += AL((size_t)N_NODES * XSTR * 2);   // h1b bf16, stride 96
  size_t OFF_AGB = o;  o += AL((size_t)N_NODES * XSTR * 2);   // xb then aggb (both stride 96)
  size_t OFF_CSR = o;  o += AL((size_t)N_EDGESC * 4);
  size_t OFF_REC = o;  o += AL((size_t)N_EDGESC * 4);
  size_t OFF_W2T = o;  o += AL((size_t)896 * 96 * 2);
  size_t OFF_W1H = o;  o += AL((size_t)96 * 96 * 2);
  size_t OFF_W1L = o;  o += AL((size_t)96 * 96 * 2);
  size_t OFF_G1H = o;  o += AL((size_t)DF1 * KP1 * 2);
  size_t OFF_G1L = o;  o += AL((size_t)DF1 * KP1 * 2);
  size_t OFF_G2H = o;  o += AL((size_t)DOUTC * DF1 * 2);
  size_t OFF_G2L = o;  o += AL((size_t)DOUTC * DF1 * 2);
  size_t OFF_ZH  = o;  o += AL((size_t)NGRAPH * KP1 * 2);
  size_t OFF_ZL  = o;  o += AL((size_t)NGRAPH * KP1 * 2);
  size_t OFF_Z1H = o;  o += AL((size_t)NGRAPH * DF1 * 2);
  size_t OFF_Z1L = o;  o += AL((size_t)NGRAPH * DF1 * 2);
  size_t OFF_RP  = o;  o += AL((size_t)(N_NODES + 1) * 4);
  size_t OFF_BOF = o;  o += AL((NBUCK + 1) * 4);
  size_t OFF_BCU = o;  o += AL(NBUCK * 4);
  size_t OFF_BC  = o;  o += AL(NBUCK * 4);                    // zero region starts here
  size_t OFF_MAX = o;  o += AL((size_t)NGRAPH * DHID * 4);
  size_t OFF_SUM = o;  o += AL((size_t)NGRAPH * DHID * 4);
  size_t OFF_CNT = o;  o += AL(NGRAPH * 4);
  size_t TOTAL = o;
  size_t ZERO0 = OFF_BC, ZEROB = TOTAL - OFF_BC;
  if (ws_size < TOTAL) return;

  size_t PB = AL((size_t)PBLK3 * DHID * 8);
  size_t OFF_PM  = OFF_AGG;   // pm/pm1 alias the 33.6MB agg-scratch region (2*10.5MB + blkg fits)
  size_t OFF_PM1 = OFF_AGG + PB;
  size_t OFF_BLG = OFF_AGG + 2 * PB;

  char* ws = (char*)d_ws;
  unsigned short* aggh = (unsigned short*)(ws + OFF_AGH);
  unsigned short* h1b = (unsigned short*)(ws + OFF_H1);
  unsigned short* aggb = (unsigned short*)(ws + OFF_AGB);
  unsigned short* xb   = (unsigned short*)(ws + OFF_AGB);   // alias: xb dead before aggb written
  int* csr   = (int*)(ws + OFF_CSR);
  unsigned int* rec = (unsigned int*)(ws + OFF_REC);
  unsigned short* w2t = (unsigned short*)(ws + OFF_W2T);
  unsigned short* w1h = (unsigned short*)(ws + OFF_W1H);
  unsigned short* w1l = (unsigned short*)(ws + OFF_W1L);
  unsigned short* g1h = (unsigned short*)(ws + OFF_G1H);
  unsigned short* g1l = (unsigned short*)(ws + OFF_G1L);
  unsigned short* g2h = (unsigned short*)(ws + OFF_G2H);
  unsigned short* g2l = (unsigned short*)(ws + OFF_G2L);
  unsigned short* zh  = (unsigned short*)(ws + OFF_ZH);
  unsigned short* zl  = (unsigned short*)(ws + OFF_ZL);
  unsigned short* z1h = (unsigned short*)(ws + OFF_Z1H);
  unsigned short* z1l = (unsigned short*)(ws + OFF_Z1L);
  int* rowptr = (int*)(ws + OFF_RP);
  int* boff  = (int*)(ws + OFF_BOF);
  int* bcur  = (int*)(ws + OFF_BCU);
  int* bcnt  = (int*)(ws + OFF_BC);
  int* maxb  = (int*)(ws + OFF_MAX);
  float* sump= (float*)(ws + OFF_SUM);
  int* cnt   = (int*)(ws + OFF_CNT);
  float2* pm  = (float2*)(ws + OFF_PM);
  float2* pm1 = (float2*)(ws + OFF_PM1);
  int* blkg  = (int*)(ws + OFF_BLG);

  hipMemsetAsync(ws + ZERO0, 0, ZEROB, stream);

  k_prep<<<PREP_B, 256, 0, stream>>>(x, xb, W2, w2t, W1, w1h, w1l, batch, cnt,
                                     Wg1, g1h, g1l, Wg2, g2h, g2l);

  int nbb = (N_EDGESC + EPB - 1) / EPB;   // 391
  k_bhist<<<nbb, 256, 0, stream>>>(dst, bcnt);
  k_bscan<<<1, 512, 0, stream>>>(bcnt, boff, bcur);
  k_bfill<<<nbb, 256, 0, stream>>>(src, dst, bcur, rec);
  k_bsort<<<NBUCK, 256, 0, stream>>>(rec, boff, rowptr, csr);

  k_agg1c<<<(N_NODES + 11) / 12, 256, 0, stream>>>(xb, rowptr, csr, aggh);
  k_conv1m2<<<PBLK3, 256, 0, stream>>>(aggh, w1h, w1l, b1, h1b);
  k_agg2<<<(N_NODES + 11) / 12, 256, 0, stream>>>(h1b, rowptr, csr, aggb);
  k_conv2pool4<<<2 * PBLK3, 256, 0, stream>>>(aggb, w2t, b2, batch, pm, pm1, blkg, maxb, sump);
  k_pool2<<<NGRAPH, 256, 0, stream>>>(pm, pm1, blkg, cnt, maxb, sump, zh, zl);

  k_mlp1m<<<(DF1 / 16) * 2, 256, 0, stream>>>(zh, zl, g1h, g1l, bg1, z1h, z1l);
  k_mlp2m<<<(DOUTC / 16) * 2, 256, 0, stream>>>(z1h, z1l, g2h, g2l, bg2, out);
}

// Round 15
// 238.600 us; speedup vs baseline: 1.0683x; 1.0359x over previous
//
#include <hip/hip_runtime.h>

#define N_NODES 100000
#define N_EDGESC 800000
#define NGRAPH 128
#define DIN 84
#define DHID 840
#define DF1 1024
#define DOUTC 384
#define PBLK3 1563  // ceil(N_NODES/64) row-tiles
#define KP1 1696    // 2*DHID padded to x32
#define NBUCK 391   // ceil(N_NODES/256)
#define EPB 2048    // edges per bucketing block
#define EBLK 391    // ceil(N_EDGESC/EPB)
#define XSTR 96     // padded row stride (192B = 3 aligned lines)

// k_prep block ranges (bhist first so CSR chain's input is ready earliest)
#define BH_B  EBLK
#define XBF_B 9375  // ceil(N_NODES*24/256)
#define W2T_B 336   // ceil(896*96/256)
#define W1T_B 36    // ceil(96*96/256)
#define CNT_B 49    // ceil(N_NODES/2048)
#define G1_B  1696  // (KP1/32)*(DF1/32)
#define G2_B  384   // (DF1/32)*(DOUTC/32)
#define PREP_B (BH_B + XBF_B + W2T_B + W1T_B + CNT_B + G1_B + G2_B)

typedef __attribute__((ext_vector_type(4))) float f32x4;
typedef __attribute__((ext_vector_type(8))) short bf16x8;

__device__ __forceinline__ unsigned short f2bf(float f) {
  union { float f; unsigned int u; } v; v.f = f;
  unsigned int r = v.u + 0x7FFFu + ((v.u >> 16) & 1u);
  return (unsigned short)(r >> 16);
}
__device__ __forceinline__ float bf2f(unsigned short h) {
  union { unsigned int u; float f; } v; v.u = ((unsigned int)h) << 16;
  return v.f;
}
__device__ __forceinline__ f32x4 bfq(uint2 p) {
  f32x4 r;
  r.x = bf2f((unsigned short)(p.x & 0xffff)); r.y = bf2f((unsigned short)(p.x >> 16));
  r.z = bf2f((unsigned short)(p.y & 0xffff)); r.w = bf2f((unsigned short)(p.y >> 16));
  return r;
}

// ---------------- fused prep: bhist | xbf | w2t | w1t | counts | wsplit x2 ----------------
__global__ __launch_bounds__(256) void k_prep(const int* __restrict__ dst, int* __restrict__ hrow,
                                              int* __restrict__ bcnt,
                                              const float* __restrict__ x, unsigned short* __restrict__ xb,
                                              const float* __restrict__ W2, unsigned short* __restrict__ w2t,
                                              const float* __restrict__ W1, unsigned short* __restrict__ w1h,
                                              unsigned short* __restrict__ w1l,
                                              const int* __restrict__ batch, int* __restrict__ cnt,
                                              const float* __restrict__ Wg1, unsigned short* __restrict__ g1h,
                                              unsigned short* __restrict__ g1l,
                                              const float* __restrict__ Wg2, unsigned short* __restrict__ g2h,
                                              unsigned short* __restrict__ g2l) {
  __shared__ float tile[32][33];
  __shared__ int h[NGRAPH];
  __shared__ int hb[NBUCK];
  int b = blockIdx.x, t = threadIdx.x;

  if (b < BH_B) {                        // bucket histogram + per-block row
    for (int i = t; i < NBUCK; i += 256) hb[i] = 0;
    __syncthreads();
    int e0 = b * EPB, e1 = min(e0 + EPB, N_EDGESC);
    for (int e = e0 + t; e < e1; e += 256) atomicAdd(&hb[dst[e] >> 8], 1);
    __syncthreads();
    for (int i = t; i < NBUCK; i += 256) {
      int c = hb[i];
      hrow[b * NBUCK + i] = c;
      if (c) atomicAdd(&bcnt[i], c);
    }
    return;
  }
  b -= BH_B;
  if (b < XBF_B) {                       // x -> bf16 stride-96 (+zero pads)
    int idx = b * 256 + t;
    if (idx >= N_NODES * 24) return;
    int r = idx / 24, c = idx - r * 24;
    uint2 p = {0u, 0u};
    if (c < 21) {
      f32x4 v = *(const f32x4*)&x[r * DIN + c * 4];
      p.x = (unsigned int)f2bf(v.x) | ((unsigned int)f2bf(v.y) << 16);
      p.y = (unsigned int)f2bf(v.z) | ((unsigned int)f2bf(v.w) << 16);
    }
    *(uint2*)&xb[r * XSTR + c * 4] = p;
    return;
  }
  b -= XBF_B;
  if (b < W2T_B) {
    int idx = b * 256 + t;
    if (idx >= 896 * 96) return;
    int n = idx / 96, k = idx % 96;
    float v = (n < DHID && k < DIN) ? W2[k * DHID + n] : 0.f;
    w2t[idx] = f2bf(v);
    return;
  }
  b -= W2T_B;
  if (b < W1T_B) {
    int idx = b * 256 + t;
    if (idx >= 96 * 96) return;
    int n = idx / 96, k = idx % 96;
    float v = (n < DIN && k < DIN) ? W1[k * DIN + n] : 0.f;
    unsigned short hh = f2bf(v);
    w1h[idx] = hh;
    w1l[idx] = f2bf(v - bf2f(hh));
    return;
  }
  b -= W1T_B;
  if (b < CNT_B) {
    if (t < NGRAPH) h[t] = 0;
    __syncthreads();
    int base = b * 2048;
    for (int j = 0; j < 8; j++) {
      int i = base + j * 256 + t;
      if (i < N_NODES) atomicAdd(&h[batch[i]], 1);
    }
    __syncthreads();
    if (t < NGRAPH && h[t] > 0) atomicAdd(&cnt[t], h[t]);
    return;
  }
  b -= CNT_B;
  const float* W; unsigned short *wh, *wl; int K, KPAD, N, vb;
  if (b < G1_B) { W = Wg1; wh = g1h; wl = g1l; K = 2 * DHID; KPAD = KP1; N = DF1; vb = b; }
  else          { W = Wg2; wh = g2h; wl = g2l; K = DF1; KPAD = DF1; N = DOUTC; vb = b - G1_B; }
  int kt = vb % (KPAD / 32), nt2 = vb / (KPAD / 32);
  int k0 = kt * 32, n0 = nt2 * 32;
  int r = t >> 3, c4 = (t & 7) * 4;
  int k = k0 + r;
  f32x4 v = {0.f, 0.f, 0.f, 0.f};
  if (k < K) v = *(const f32x4*)&W[(size_t)k * N + n0 + c4];
  tile[r][c4 + 0] = v.x; tile[r][c4 + 1] = v.y; tile[r][c4 + 2] = v.z; tile[r][c4 + 3] = v.w;
  __syncthreads();
  int n = t >> 3;
  float f0 = tile[c4 + 0][n], f1 = tile[c4 + 1][n], f2 = tile[c4 + 2][n], f3 = tile[c4 + 3][n];
  unsigned short h0 = f2bf(f0), h1_ = f2bf(f1), h2_ = f2bf(f2), h3_ = f2bf(f3);
  uint2 ph, pl;
  ph.x = (unsigned int)h0 | ((unsigned int)h1_ << 16);
  ph.y = (unsigned int)h2_ | ((unsigned int)h3_ << 16);
  pl.x = (unsigned int)f2bf(f0 - bf2f(h0)) | ((unsigned int)f2bf(f1 - bf2f(h1_)) << 16);
  pl.y = (unsigned int)f2bf(f2 - bf2f(h2_)) | ((unsigned int)f2bf(f3 - bf2f(h3_)) << 16);
  *(uint2*)&wh[(size_t)(n0 + n) * KPAD + k0 + c4] = ph;
  *(uint2*)&wl[(size_t)(n0 + n) * KPAD + k0 + c4] = pl;
}

// ---------------- bcolscan: boff[g] = sum bcnt[<g]; hrow[blk][g] -> deterministic base ----
__global__ __launch_bounds__(512) void k_bcolscan(const int* __restrict__ bcnt, int* __restrict__ hrow,
                                                  int* __restrict__ boff) {
  __shared__ int sr[512];
  __shared__ int sd[512];
  int g = blockIdx.x, t = threadIdx.x;
  sr[t] = (t < g) ? bcnt[t] : 0;
  __syncthreads();
  for (int off = 256; off > 0; off >>= 1) {
    if (t < off) sr[t] += sr[t + off];
    __syncthreads();
  }
  int base0 = sr[0];
  if (t == 0) boff[g] = base0;
  if (g == 0 && t == 0) boff[NBUCK] = N_EDGESC;
  int v = (t < EBLK) ? hrow[t * NBUCK + g] : 0;
  sd[t] = v;
  __syncthreads();
  for (int off = 1; off < 512; off <<= 1) {
    int add = (t >= off) ? sd[t - off] : 0;
    __syncthreads();
    sd[t] += add;
    __syncthreads();
  }
  if (t < EBLK) hrow[t * NBUCK + g] = base0 + sd[t] - v;   // exclusive base
}

// ---------------- bfill2: single edge pass, deterministic bases, no global atomics --------
__global__ __launch_bounds__(256) void k_bfill2(const int* __restrict__ src, const int* __restrict__ dst,
                                                const int* __restrict__ hrow, unsigned int* __restrict__ rec) {
  __shared__ int hcnt[NBUCK];
  __shared__ int hbase[NBUCK];
  int t = threadIdx.x, b = blockIdx.x;
  for (int i = t; i < NBUCK; i += 256) { hcnt[i] = 0; hbase[i] = hrow[b * NBUCK + i]; }
  __syncthreads();
  int e0 = b * EPB, e1 = min(e0 + EPB, N_EDGESC);
  for (int e = e0 + t; e < e1; e += 256) {
    int d = dst[e];
    int bk = d >> 8;
    int r = atomicAdd(&hcnt[bk], 1);
    rec[hbase[bk] + r] = ((unsigned int)(d & 255) << 24) | (unsigned int)src[e];
  }
}

__global__ __launch_bounds__(256) void k_bsort(const unsigned int* __restrict__ rec, const int* __restrict__ boff,
                                               int* __restrict__ rowptr, int* __restrict__ csr) {
  __shared__ int lcnt[256];
  __shared__ int lcur[256];
  int b = blockIdx.x, t = threadIdx.x;
  int e0 = boff[b], e1 = boff[b + 1];
  lcnt[t] = 0;
  __syncthreads();
  for (int i = e0 + t; i < e1; i += 256) atomicAdd(&lcnt[rec[i] >> 24], 1);
  __syncthreads();
  int v = lcnt[t];
  for (int off = 1; off < 256; off <<= 1) {
    int add = (t >= off) ? lcnt[t - off] : 0;
    __syncthreads();
    lcnt[t] += add;
    __syncthreads();
  }
  int excl = lcnt[t] - v;
  int node = b * 256 + t;
  if (node < N_NODES) rowptr[node] = e0 + excl;
  lcur[t] = e0 + excl;
  if (b == NBUCK - 1 && t == 0) rowptr[N_NODES] = N_EDGESC;
  __syncthreads();
  for (int i = e0 + t; i < e1; i += 256) {
    unsigned int r = rec[i];
    int d = r >> 24;
    int pos = atomicAdd(&lcur[d], 1);
    csr[pos] = (int)(r & 0xFFFFFFu);
  }
}

// ---------------- agg1c: bf16 gather (stride 96) -> bf16 out (stride 96, zero-pad) -------
__global__ __launch_bounds__(256) void k_agg1c(const unsigned short* __restrict__ xb,
                                               const int* __restrict__ rowptr,
                                               const int* __restrict__ csr,
                                               unsigned short* __restrict__ aggh) {
  int t = threadIdx.x;
  int wv = t >> 6, l = t & 63;
  int grp = (l >= 42) ? 2 : (l >= 21 ? 1 : 0);
  int li = l - grp * 21;
  int node = blockIdx.x * 12 + wv * 3 + grp;
  bool act = (li < 21) && (node < N_NODES);
  if (l == 63) {
    uint2 z = {0u, 0u};
    for (int g = 0; g < 3; g++) {
      int nd = blockIdx.x * 12 + wv * 3 + g;
      if (nd < N_NODES) {
        *(uint2*)&aggh[nd * XSTR + 84] = z; *(uint2*)&aggh[nd * XSTR + 88] = z; *(uint2*)&aggh[nd * XSTR + 92] = z;
      }
    }
  }
  int nclamp = min(node, N_NODES - 1);
  int r0 = rowptr[nclamp];
  int r1 = act ? rowptr[nclamp + 1] : r0;
  f32x4 a = {0.f, 0.f, 0.f, 0.f};
  if (act) a = bfq(*(const uint2*)&xb[nclamp * XSTR + li * 4]);
  int e = r0;
  for (; e + 8 <= r1; e += 8) {
    int s0 = csr[e], s1 = csr[e + 1], s2 = csr[e + 2], s3 = csr[e + 3];
    int s4 = csr[e + 4], s5 = csr[e + 5], s6 = csr[e + 6], s7 = csr[e + 7];
    uint2 q0 = *(const uint2*)&xb[s0 * XSTR + li * 4];
    uint2 q1 = *(const uint2*)&xb[s1 * XSTR + li * 4];
    uint2 q2 = *(const uint2*)&xb[s2 * XSTR + li * 4];
    uint2 q3 = *(const uint2*)&xb[s3 * XSTR + li * 4];
    uint2 q4 = *(const uint2*)&xb[s4 * XSTR + li * 4];
    uint2 q5 = *(const uint2*)&xb[s5 * XSTR + li * 4];
    uint2 q6 = *(const uint2*)&xb[s6 * XSTR + li * 4];
    uint2 q7 = *(const uint2*)&xb[s7 * XSTR + li * 4];
    a += ((bfq(q0) + bfq(q1)) + (bfq(q2) + bfq(q3))) + ((bfq(q4) + bfq(q5)) + (bfq(q6) + bfq(q7)));
  }
  for (; e + 4 <= r1; e += 4) {
    int s0 = csr[e], s1 = csr[e + 1], s2 = csr[e + 2], s3 = csr[e + 3];
    uint2 q0 = *(const uint2*)&xb[s0 * XSTR + li * 4];
    uint2 q1 = *(const uint2*)&xb[s1 * XSTR + li * 4];
    uint2 q2 = *(const uint2*)&xb[s2 * XSTR + li * 4];
    uint2 q3 = *(const uint2*)&xb[s3 * XSTR + li * 4];
    a += (bfq(q0) + bfq(q1)) + (bfq(q2) + bfq(q3));
  }
  for (; e < r1; e++) {
    int s = csr[e];
    a += bfq(*(const uint2*)&xb[s * XSTR + li * 4]);
  }
  if (act) {
    uint2 p;
    p.x = (unsigned int)f2bf(a.x) | ((unsigned int)f2bf(a.y) << 16);
    p.y = (unsigned int)f2bf(a.z) | ((unsigned int)f2bf(a.w) << 16);
    *(uint2*)&aggh[node * XSTR + li * 4] = p;
  }
}

// ---------------- conv1m2: MFMA from global bf16 A (no LDS), split W1, h1b bf16 out -------
__global__ __launch_bounds__(256) void k_conv1m2(const unsigned short* __restrict__ aggh,
                                                 const unsigned short* __restrict__ w1h,
                                                 const unsigned short* __restrict__ w1l,
                                                 const float* __restrict__ b1,
                                                 unsigned short* __restrict__ h1b) {
  int t = threadIdx.x;
  int m0 = blockIdx.x * 64;
  int wv = t >> 6, l = t & 63;
  int lr = l & 15, lk = (l >> 4) * 8;
  int row = m0 + wv * 16 + lr;
  bool inb = row < N_NODES;
  bf16x8 ah[3];
  #pragma unroll
  for (int kk = 0; kk < 3; kk++) {
    bf16x8 vh = {0, 0, 0, 0, 0, 0, 0, 0};
    if (inb) vh = *(const bf16x8*)&aggh[(size_t)row * XSTR + lk + kk * 32];
    ah[kk] = vh;
  }
  #pragma unroll
  for (int nt = 0; nt < 6; nt++) {
    f32x4 acc = {0.f, 0.f, 0.f, 0.f};
    #pragma unroll
    for (int kk = 0; kk < 3; kk++) {
      bf16x8 bh = *(const bf16x8*)&w1h[(nt * 16 + lr) * 96 + lk + kk * 32];
      bf16x8 bl = *(const bf16x8*)&w1l[(nt * 16 + lr) * 96 + lk + kk * 32];
      acc = __builtin_amdgcn_mfma_f32_16x16x32_bf16(ah[kk], bh, acc, 0, 0, 0);
      acc = __builtin_amdgcn_mfma_f32_16x16x32_bf16(ah[kk], bl, acc, 0, 0, 0);
    }
    int col = nt * 16 + lr;
    if (col < DIN) {
      float bias = b1[col];
      int rbase = m0 + wv * 16 + (l >> 4) * 4;
      #pragma unroll
      for (int j = 0; j < 4; j++) {
        if (rbase + j < N_NODES)
          h1b[(rbase + j) * XSTR + col] = f2bf(fmaxf(acc[j] + bias, 0.f));
      }
    }
  }
}

// ---------------- agg2: bf16 in (stride 96), bf16 out cols 0..83 (stride 96) -------------
__global__ __launch_bounds__(256) void k_agg2(const unsigned short* __restrict__ h1b, const int* __restrict__ rowptr,
                                              const int* __restrict__ csr, unsigned short* __restrict__ out) {
  int t = threadIdx.x;
  int wv = t >> 6, l = t & 63;
  int grp = (l >= 42) ? 2 : (l >= 21 ? 1 : 0);
  int li = l - grp * 21;
  int node = blockIdx.x * 12 + wv * 3 + grp;
  bool act = (li < 21) && (node < N_NODES);
  int nclamp = min(node, N_NODES - 1);
  int r0 = rowptr[nclamp];
  int r1 = act ? rowptr[nclamp + 1] : r0;
  f32x4 a = {0.f, 0.f, 0.f, 0.f};
  if (act) a = bfq(*(const uint2*)&h1b[nclamp * XSTR + li * 4]);
  int e = r0;
  for (; e + 8 <= r1; e += 8) {
    int s0 = csr[e], s1 = csr[e + 1], s2 = csr[e + 2], s3 = csr[e + 3];
    int s4 = csr[e + 4], s5 = csr[e + 5], s6 = csr[e + 6], s7 = csr[e + 7];
    uint2 q0 = *(const uint2*)&h1b[s0 * XSTR + li * 4];
    uint2 q1 = *(const uint2*)&h1b[s1 * XSTR + li * 4];
    uint2 q2 = *(const uint2*)&h1b[s2 * XSTR + li * 4];
    uint2 q3 = *(const uint2*)&h1b[s3 * XSTR + li * 4];
    uint2 q4 = *(const uint2*)&h1b[s4 * XSTR + li * 4];
    uint2 q5 = *(const uint2*)&h1b[s5 * XSTR + li * 4];
    uint2 q6 = *(const uint2*)&h1b[s6 * XSTR + li * 4];
    uint2 q7 = *(const uint2*)&h1b[s7 * XSTR + li * 4];
    a += ((bfq(q0) + bfq(q1)) + (bfq(q2) + bfq(q3))) + ((bfq(q4) + bfq(q5)) + (bfq(q6) + bfq(q7)));
  }
  for (; e + 4 <= r1; e += 4) {
    int s0 = csr[e], s1 = csr[e + 1], s2 = csr[e + 2], s3 = csr[e + 3];
    uint2 q0 = *(const uint2*)&h1b[s0 * XSTR + li * 4];
    uint2 q1 = *(const uint2*)&h1b[s1 * XSTR + li * 4];
    uint2 q2 = *(const uint2*)&h1b[s2 * XSTR + li * 4];
    uint2 q3 = *(const uint2*)&h1b[s3 * XSTR + li * 4];
    a += (bfq(q0) + bfq(q1)) + (bfq(q2) + bfq(q3));
  }
  for (; e < r1; e++) {
    int s = csr[e];
    a += bfq(*(const uint2*)&h1b[s * XSTR + li * 4]);
  }
  if (act) {
    uint2 p;
    p.x = (unsigned int)f2bf(a.x) | ((unsigned int)f2bf(a.y) << 16);
    p.y = (unsigned int)f2bf(a.z) | ((unsigned int)f2bf(a.w) << 16);
    *(uint2*)&out[node * XSTR + li * 4] = p;
  }
}

// ---------------- conv2 + pooling stage 1: 64-row tiles x 2 column-halves ----------------
__global__ __launch_bounds__(256) void k_conv2pool4(const unsigned short* __restrict__ aggb,
                                                    const unsigned short* __restrict__ w2t,
                                                    const float* __restrict__ b2,
                                                    const int* __restrict__ batch,
                                                    float2* __restrict__ pm, float2* __restrict__ pm1,
                                                    int* __restrict__ blkg,
                                                    int* __restrict__ maxb, float* __restrict__ sump) {
  constexpr int LDA = 104;
  __shared__ __align__(16) unsigned short At[64 * LDA];
  int t = threadIdx.x;
  int w = t >> 6, l = t & 63;
  int b = blockIdx.x >> 1;
  int half = blockIdx.x & 1;
  int m0 = b * 64;
  int lr = l & 15, hi = l >> 4, lk = hi * 8;

  for (int idx = t; idx < 64 * 12; idx += 256) {
    int r = idx / 12, c = idx - r * 12;
    uint4 v = {0u, 0u, 0u, 0u};
    int row = m0 + r;
    if (row < N_NODES) v = *(const uint4*)&aggb[row * XSTR + c * 8];
    *(uint4*)&At[r * LDA + c * 8] = v;
  }
  int g0 = batch[m0];
  int g1 = batch[min(m0 + 63, N_NODES - 1)];
  bool fast = (g0 == g1) && (m0 + 63 < N_NODES);
  __syncthreads();

  bf16x8 afr[4][3];
  #pragma unroll
  for (int rg = 0; rg < 4; rg++)
    #pragma unroll
    for (int kk = 0; kk < 3; kk++)
      afr[rg][kk] = *(bf16x8*)&At[(rg * 16 + lr) * LDA + lk + kk * 32];

  int pbase = half * 28 + w * 7;

  if (fast) {
    for (int i = 0; i < 7; i++) {
      int c = (pbase + i) * 16 + lr;
      const unsigned short* bp = &w2t[c * 96 + lk];
      bf16x8 b0v = *(const bf16x8*)(bp);
      bf16x8 b1v = *(const bf16x8*)(bp + 32);
      bf16x8 b2v = *(const bf16x8*)(bp + 64);
      float bias = (c < DHID) ? b2[c] : 0.f;
      float mx = 0.f, sm = 0.f;
      #pragma unroll
      for (int rg = 0; rg < 4; rg++) {
        f32x4 a_ = {0.f, 0.f, 0.f, 0.f};
        a_ = __builtin_amdgcn_mfma_f32_16x16x32_bf16(afr[rg][0], b0v, a_, 0, 0, 0);
        a_ = __builtin_amdgcn_mfma_f32_16x16x32_bf16(afr[rg][1], b1v, a_, 0, 0, 0);
        a_ = __builtin_amdgcn_mfma_f32_16x16x32_bf16(afr[rg][2], b2v, a_, 0, 0, 0);
        float v0 = fmaxf(a_[0] + bias, 0.f);
        float v1 = fmaxf(a_[1] + bias, 0.f);
        float v2 = fmaxf(a_[2] + bias, 0.f);
        float v3 = fmaxf(a_[3] + bias, 0.f);
        mx = fmaxf(mx, fmaxf(fmaxf(v0, v1), fmaxf(v2, v3)));
        sm += (v0 + v1) + (v2 + v3);
      }
      mx = fmaxf(mx, __shfl_xor(mx, 16)); sm += __shfl_xor(sm, 16);
      mx = fmaxf(mx, __shfl_xor(mx, 32)); sm += __shfl_xor(sm, 32);
      if (hi == 0 && c < DHID) pm[(size_t)b * DHID + c] = make_float2(mx, sm);
    }
  } else {
    int grow[4][4];
    #pragma unroll
    for (int rg = 0; rg < 4; rg++)
      #pragma unroll
      for (int j = 0; j < 4; j++) {
        int row = m0 + rg * 16 + hi * 4 + j;
        grow[rg][j] = (row < N_NODES) ? batch[row] : -1;
      }
    for (int i = 0; i < 7; i++) {
      int c = (pbase + i) * 16 + lr;
      const unsigned short* bp = &w2t[c * 96 + lk];
      bf16x8 b0v = *(const bf16x8*)(bp);
      bf16x8 b1v = *(const bf16x8*)(bp + 32);
      bf16x8 b2v = *(const bf16x8*)(bp + 64);
      float bias = (c < DHID) ? b2[c] : 0.f;
      float mx0 = 0.f, sm0 = 0.f, mx1 = 0.f, sm1 = 0.f;
      float vv[4][4];
      #pragma unroll
      for (int rg = 0; rg < 4; rg++) {
        f32x4 a_ = {0.f, 0.f, 0.f, 0.f};
        a_ = __builtin_amdgcn_mfma_f32_16x16x32_bf16(afr[rg][0], b0v, a_, 0, 0, 0);
        a_ = __builtin_amdgcn_mfma_f32_16x16x32_bf16(afr[rg][1], b1v, a_, 0, 0, 0);
        a_ = __builtin_amdgcn_mfma_f32_16x16x32_bf16(afr[rg][2], b2v, a_, 0, 0, 0);
        #pragma unroll
        for (int j = 0; j < 4; j++) {
          float v = fmaxf(a_[j] + bias, 0.f);
          vv[rg][j] = v;
          if (grow[rg][j] == g0) { mx0 = fmaxf(mx0, v); sm0 += v; }
          if (grow[rg][j] == g1) { mx1 = fmaxf(mx1, v); sm1 += v; }
        }
      }
      mx0 = fmaxf(mx0, __shfl_xor(mx0, 16)); sm0 += __shfl_xor(sm0, 16);
      mx0 = fmaxf(mx0, __shfl_xor(mx0, 32)); sm0 += __shfl_xor(sm0, 32);
      mx1 = fmaxf(mx1, __shfl_xor(mx1, 16)); sm1 += __shfl_xor(sm1, 16);
      mx1 = fmaxf(mx1, __shfl_xor(mx1, 32)); sm1 += __shfl_xor(sm1, 32);
      if (hi == 0 && c < DHID) {
        pm[(size_t)b * DHID + c] = make_float2(mx0, sm0);
        pm1[(size_t)b * DHID + c] = make_float2(mx1, sm1);
      }
      if (g1 - g0 >= 2) {
        for (int g = g0 + 1; g < g1; g++) {
          float mx = 0.f, sm = 0.f;
          #pragma unroll
          for (int rg = 0; rg < 4; rg++)
            #pragma unroll
            for (int j = 0; j < 4; j++)
              if (grow[rg][j] == g) { mx = fmaxf(mx, vv[rg][j]); sm += vv[rg][j]; }
          mx = fmaxf(mx, __shfl_xor(mx, 16)); sm += __shfl_xor(sm, 16);
          mx = fmaxf(mx, __shfl_xor(mx, 32)); sm += __shfl_xor(sm, 32);
          if (hi == 0 && c < DHID) {
            atomicMax(&maxb[g * DHID + c], __float_as_int(mx));
            atomicAdd(&sump[g * DHID + c], sm);
          }
        }
      }
    }
  }
  if (t == 0 && half == 0) { blkg[b * 2] = g0; blkg[b * 2 + 1] = g1; }
}

// ---------------- pooling stage 2: merge partials, emit z as hi/lo bf16 [128][KP1] --------
__global__ __launch_bounds__(256) void k_pool2(const float2* __restrict__ pm, const float2* __restrict__ pm1,
                                               const int* __restrict__ blkg, const int* __restrict__ cnt,
                                               const int* __restrict__ maxb, const float* __restrict__ sump,
                                               unsigned short* __restrict__ zh, unsigned short* __restrict__ zl) {
  __shared__ int sstart[NGRAPH];
  int g = blockIdx.x, t = threadIdx.x;
  if (t == 0) {
    int s = 0;
    for (int i = 0; i < NGRAPH; i++) { sstart[i] = s; s += cnt[i]; }
  }
  __syncthreads();
  int c0 = cnt[g];
  int ns = sstart[g], ne = ns + c0;
  int b0 = ns / 64, b1 = (c0 > 0) ? (ne - 1) / 64 : b0 - 1;
  for (int c = t; c < DHID; c += 256) {
    float mx = __int_as_float(maxb[g * DHID + c]);
    float sm = sump[g * DHID + c];
    for (int b = b0; b <= b1; b++) {
      int gg0 = blkg[2 * b], gg1 = blkg[2 * b + 1];
      if (gg0 == g)      { float2 p = pm[(size_t)b * DHID + c];  mx = fmaxf(mx, p.x); sm += p.y; }
      else if (gg1 == g) { float2 p = pm1[(size_t)b * DHID + c]; mx = fmaxf(mx, p.x); sm += p.y; }
    }
    float vmax = (c0 > 0) ? mx : 0.f;
    float vmean = sm / (float)max(c0, 1);
    unsigned short hm = f2bf(vmax);
    zh[g * KP1 + c] = hm;
    zl[g * KP1 + c] = f2bf(vmax - bf2f(hm));
    unsigned short he = f2bf(vmean);
    zh[g * KP1 + DHID + c] = he;
    zl[g * KP1 + DHID + c] = f2bf(vmean - bf2f(he));
  }
  if (t < KP1 - 2 * DHID) {
    zh[g * KP1 + 2 * DHID + t] = 0;
    zl[g * KP1 + 2 * DHID + t] = 0;
  }
}

// ---------------- MLP1: z1 = relu(z @ Wg1 + bg1), split-bf16 MFMA, hi/lo out ----------------
__global__ __launch_bounds__(256) void k_mlp1m(const unsigned short* __restrict__ zh, const unsigned short* __restrict__ zl,
                                               const unsigned short* __restrict__ wh, const unsigned short* __restrict__ wl,
                                               const float* __restrict__ bg,
                                               unsigned short* __restrict__ z1h, unsigned short* __restrict__ z1l) {
  int t = threadIdx.x, w = t >> 6, l = t & 63;
  int lr = l & 15, hi = l >> 4, lk = hi * 8;
  int b = blockIdx.x;
  int n0 = (b >> 1) * 16;
  int m0 = (b & 1) * 64 + w * 16;
  const unsigned short* za = &zh[(size_t)(m0 + lr) * KP1 + lk];
  const unsigned short* zb = &zl[(size_t)(m0 + lr) * KP1 + lk];
  const unsigned short* wa = &wh[(size_t)(n0 + lr) * KP1 + lk];
  const unsigned short* wb = &wl[(size_t)(n0 + lr) * KP1 + lk];
  f32x4 acc = {0.f, 0.f, 0.f, 0.f};
  for (int ks = 0; ks < KP1 / 32; ks++) {
    bf16x8 ah = *(const bf16x8*)(za + ks * 32);
    bf16x8 al = *(const bf16x8*)(zb + ks * 32);
    bf16x8 bh = *(const bf16x8*)(wa + ks * 32);
    bf16x8 bl = *(const bf16x8*)(wb + ks * 32);
    acc = __builtin_amdgcn_mfma_f32_16x16x32_bf16(ah, bh, acc, 0, 0, 0);
    acc = __builtin_amdgcn_mfma_f32_16x16x32_bf16(al, bh, acc, 0, 0, 0);
    acc = __builtin_amdgcn_mfma_f32_16x16x32_bf16(ah, bl, acc, 0, 0, 0);
  }
  int col = n0 + lr;
  float bias = bg[col];
  #pragma unroll
  for (int j = 0; j < 4; j++) {
    int row = m0 + hi * 4 + j;
    float v = fmaxf(acc[j] + bias, 0.f);
    unsigned short h = f2bf(v);
    z1h[row * DF1 + col] = h;
    z1l[row * DF1 + col] = f2bf(v - bf2f(h));
  }
}

// ---------------- MLP2: out = z1 @ Wg2 + bg2, split-bf16 MFMA, f32 out ----------------
__global__ __launch_bounds__(256) void k_mlp2m(const unsigned short* __restrict__ z1h, const unsigned short* __restrict__ z1l,
                                               const unsigned short* __restrict__ wh, const unsigned short* __restrict__ wl,
                                               const float* __restrict__ bg, float* __restrict__ out) {
  int t = threadIdx.x, w = t >> 6, l = t & 63;
  int lr = l & 15, hi = l >> 4, lk = hi * 8;
  int b = blockIdx.x;
  int n0 = (b >> 1) * 16;
  int m0 = (b & 1) * 64 + w * 16;
  const unsigned short* za = &z1h[(size_t)(m0 + lr) * DF1 + lk];
  const unsigned short* zb = &z1l[(size_t)(m0 + lr) * DF1 + lk];
  const unsigned short* wa = &wh[(size_t)(n0 + lr) * DF1 + lk];
  const unsigned short* wb = &wl[(size_t)(n0 + lr) * DF1 + lk];
  f32x4 acc = {0.f, 0.f, 0.f, 0.f};
  for (int ks = 0; ks < DF1 / 32; ks++) {
    bf16x8 ah = *(const bf16x8*)(za + ks * 32);
    bf16x8 al = *(const bf16x8*)(zb + ks * 32);
    bf16x8 bh = *(const bf16x8*)(wa + ks * 32);
    bf16x8 bl = *(const bf16x8*)(wb + ks * 32);
    acc = __builtin_amdgcn_mfma_f32_16x16x32_bf16(ah, bh, acc, 0, 0, 0);
    acc = __builtin_amdgcn_mfma_f32_16x16x32_bf16(al, bh, acc, 0, 0, 0);
    acc = __builtin_amdgcn_mfma_f32_16x16x32_bf16(ah, bl, acc, 0, 0, 0);
  }
  int col = n0 + lr;
  float bias = bg[col];
  #pragma unroll
  for (int j = 0; j < 4; j++) {
    int row = m0 + hi * 4 + j;
    out[row * DOUTC + col] = acc[j] + bias;
  }
}

// ---------------- launch ----------------
static constexpr size_t AL(size_t x) { return (x + 255) & ~(size_t)255; }

extern "C" void kernel_launch(void* const* d_in, const int* in_sizes, int n_in,
                              void* d_out, int out_size, void* d_ws, size_t ws_size,
                              hipStream_t stream) {
  const float* x   = (const float*)d_in[0];
  const int*  edge = (const int*)d_in[1];
  const int*  batch= (const int*)d_in[2];
  const float* W1  = (const float*)d_in[3];
  const float* b1  = (const float*)d_in[4];
  const float* W2  = (const float*)d_in[5];
  const float* b2  = (const float*)d_in[6];
  const float* Wg1 = (const float*)d_in[7];
  const float* bg1 = (const float*)d_in[8];
  const float* Wg2 = (const float*)d_in[9];
  const float* bg2 = (const float*)d_in[10];
  float* out = (float*)d_out;
  const int* src = edge;
  const int* dst = edge + N_EDGESC;

  size_t o = 0;
  size_t OFF_AGG = o;  o += AL((size_t)N_NODES * DIN * 4);    // pooling partials scratch
  size_t OFF_AGH = o;  o += AL((size_t)N_NODES * XSTR * 2);   // aggh bf16
  size_t OFF_H1  = o;  o += AL((size_t)N_NODES * XSTR * 2);   // h1b bf16, stride 96
  size_t OFF_AGB = o;  o += AL((size_t)N_NODES * XSTR * 2);   // xb then aggb (both stride 96)
  size_t OFF_CSR = o;  o += AL((size_t)N_EDGESC * 4);
  size_t OFF_REC = o;  o += AL((size_t)N_EDGESC * 4);
  size_t OFF_HRW = o;  o += AL((size_t)EBLK * NBUCK * 4);     // per-block bucket hist -> bases
  size_t OFF_W2T = o;  o += AL((size_t)896 * 96 * 2);
  size_t OFF_W1H = o;  o += AL((size_t)96 * 96 * 2);
  size_t OFF_W1L = o;  o += AL((size_t)96 * 96 * 2);
  size_t OFF_G1H = o;  o += AL((size_t)DF1 * KP1 * 2);
  size_t OFF_G1L = o;  o += AL((size_t)DF1 * KP1 * 2);
  size_t OFF_G2H = o;  o += AL((size_t)DOUTC * DF1 * 2);
  size_t OFF_G2L = o;  o += AL((size_t)DOUTC * DF1 * 2);
  size_t OFF_ZH  = o;  o += AL((size_t)NGRAPH * KP1 * 2);
  size_t OFF_ZL  = o;  o += AL((size_t)NGRAPH * KP1 * 2);
  size_t OFF_Z1H = o;  o += AL((size_t)NGRAPH * DF1 * 2);
  size_t OFF_Z1L = o;  o += AL((size_t)NGRAPH * DF1 * 2);
  size_t OFF_RP  = o;  o += AL((size_t)(N_NODES + 1) * 4);
  size_t OFF_BOF = o;  o += AL((NBUCK + 1) * 4);
  size_t OFF_BC  = o;  o += AL(NBUCK * 4);                    // zero region starts here
  size_t OFF_MAX = o;  o += AL((size_t)NGRAPH * DHID * 4);
  size_t OFF_SUM = o;  o += AL((size_t)NGRAPH * DHID * 4);
  size_t OFF_CNT = o;  o += AL(NGRAPH * 4);
  size_t TOTAL = o;
  size_t ZERO0 = OFF_BC, ZEROB = TOTAL - OFF_BC;
  if (ws_size < TOTAL) return;

  size_t PB = AL((size_t)PBLK3 * DHID * 8);
  size_t OFF_PM  = OFF_AGG;   // pm/pm1 alias the 33.6MB agg-scratch region (2*10.5MB + blkg fits)
  size_t OFF_PM1 = OFF_AGG + PB;
  size_t OFF_BLG = OFF_AGG + 2 * PB;

  char* ws = (char*)d_ws;
  unsigned short* aggh = (unsigned short*)(ws + OFF_AGH);
  unsigned short* h1b = (unsigned short*)(ws + OFF_H1);
  unsigned short* aggb = (unsigned short*)(ws + OFF_AGB);
  unsigned short* xb   = (unsigned short*)(ws + OFF_AGB);   // alias: xb dead before aggb written
  int* csr   = (int*)(ws + OFF_CSR);
  unsigned int* rec = (unsigned int*)(ws + OFF_REC);
  int* hrow  = (int*)(ws + OFF_HRW);
  unsigned short* w2t = (unsigned short*)(ws + OFF_W2T);
  unsigned short* w1h = (unsigned short*)(ws + OFF_W1H);
  unsigned short* w1l = (unsigned short*)(ws + OFF_W1L);
  unsigned short* g1h = (unsigned short*)(ws + OFF_G1H);
  unsigned short* g1l = (unsigned short*)(ws + OFF_G1L);
  unsigned short* g2h = (unsigned short*)(ws + OFF_G2H);
  unsigned short* g2l = (unsigned short*)(ws + OFF_G2L);
  unsigned short* zh  = (unsigned short*)(ws + OFF_ZH);
  unsigned short* zl  = (unsigned short*)(ws + OFF_ZL);
  unsigned short* z1h = (unsigned short*)(ws + OFF_Z1H);
  unsigned short* z1l = (unsigned short*)(ws + OFF_Z1L);
  int* rowptr = (int*)(ws + OFF_RP);
  int* boff  = (int*)(ws + OFF_BOF);
  int* bcnt  = (int*)(ws + OFF_BC);
  int* maxb  = (int*)(ws + OFF_MAX);
  float* sump= (float*)(ws + OFF_SUM);
  int* cnt   = (int*)(ws + OFF_CNT);
  float2* pm  = (float2*)(ws + OFF_PM);
  float2* pm1 = (float2*)(ws + OFF_PM1);
  int* blkg  = (int*)(ws + OFF_BLG);

  hipMemsetAsync(ws + ZERO0, 0, ZEROB, stream);

  k_prep<<<PREP_B, 256, 0, stream>>>(dst, hrow, bcnt, x, xb, W2, w2t, W1, w1h, w1l,
                                     batch, cnt, Wg1, g1h, g1l, Wg2, g2h, g2l);
  k_bcolscan<<<NBUCK, 512, 0, stream>>>(bcnt, hrow, boff);
  k_bfill2<<<EBLK, 256, 0, stream>>>(src, dst, hrow, rec);
  k_bsort<<<NBUCK, 256, 0, stream>>>(rec, boff, rowptr, csr);

  k_agg1c<<<(N_NODES + 11) / 12, 256, 0, stream>>>(xb, rowptr, csr, aggh);
  k_conv1m2<<<PBLK3, 256, 0, stream>>>(aggh, w1h, w1l, b1, h1b);
  k_agg2<<<(N_NODES + 11) / 12, 256, 0, stream>>>(h1b, rowptr, csr, aggb);
  k_conv2pool4<<<2 * PBLK3, 256, 0, stream>>>(aggb, w2t, b2, batch, pm, pm1, blkg, maxb, sump);
  k_pool2<<<NGRAPH, 256, 0, stream>>>(pm, pm1, blkg, cnt, maxb, sump, zh, zl);

  k_mlp1m<<<(DF1 / 16) * 2, 256, 0, stream>>>(zh, zl, g1h, g1l, bg1, z1h, z1l);
  k_mlp2m<<<(DOUTC / 16) * 2, 256, 0, stream>>>(z1h, z1l, g2h, g2l, bg2, out);
}

// Round 16
// 234.693 us; speedup vs baseline: 1.0861x; 1.0166x over previous
//
#include <hip/hip_runtime.h>

#define N_NODES 100000
#define N_EDGESC 800000
#define NGRAPH 128
#define DIN 84
#define DHID 840
#define DF1 1024
#define DOUTC 384
#define PBLK3 1563  // ceil(N_NODES/64) row-tiles
#define KP1 1696    // 2*DHID padded to x32
#define NBUCK 391   // ceil(N_NODES/256)
#define EPB 2048    // edges per bucketing block
#define EBLK 391    // ceil(N_EDGESC/EPB)
#define XSTR 96     // padded row stride (192B = 3 aligned lines)

// k_prep block ranges (bhist first so CSR chain's input is ready earliest)
#define BH_B  EBLK
#define XBF_B 9375  // ceil(N_NODES*24/256)
#define W2T_B 336   // ceil(896*96/256)
#define W1T_B 36    // ceil(96*96/256)
#define CNT_B 49    // ceil(N_NODES/2048)
#define G1_B  1696  // (KP1/32)*(DF1/32)
#define G2_B  384   // (DF1/32)*(DOUTC/32)
#define PREP_B (BH_B + XBF_B + W2T_B + W1T_B + CNT_B + G1_B + G2_B)

typedef __attribute__((ext_vector_type(4))) float f32x4;
typedef __attribute__((ext_vector_type(8))) short bf16x8;

__device__ __forceinline__ unsigned short f2bf(float f) {
  union { float f; unsigned int u; } v; v.f = f;
  unsigned int r = v.u + 0x7FFFu + ((v.u >> 16) & 1u);
  return (unsigned short)(r >> 16);
}
__device__ __forceinline__ float bf2f(unsigned short h) {
  union { unsigned int u; float f; } v; v.u = ((unsigned int)h) << 16;
  return v.f;
}
__device__ __forceinline__ f32x4 bfq(uint2 p) {
  f32x4 r;
  r.x = bf2f((unsigned short)(p.x & 0xffff)); r.y = bf2f((unsigned short)(p.x >> 16));
  r.z = bf2f((unsigned short)(p.y & 0xffff)); r.w = bf2f((unsigned short)(p.y >> 16));
  return r;
}

// ---------------- fused prep: bhist | xbf | w2t | w1t | counts | wsplit x2 ----------------
__global__ __launch_bounds__(256) void k_prep(const int* __restrict__ dst, int* __restrict__ hrow,
                                              int* __restrict__ bcnt,
                                              const float* __restrict__ x, unsigned short* __restrict__ xb,
                                              const float* __restrict__ W2, unsigned short* __restrict__ w2t,
                                              const float* __restrict__ W1, unsigned short* __restrict__ w1h,
                                              unsigned short* __restrict__ w1l,
                                              const int* __restrict__ batch, int* __restrict__ cnt,
                                              const float* __restrict__ Wg1, unsigned short* __restrict__ g1h,
                                              unsigned short* __restrict__ g1l,
                                              const float* __restrict__ Wg2, unsigned short* __restrict__ g2h,
                                              unsigned short* __restrict__ g2l) {
  __shared__ float tile[32][33];
  __shared__ int h[NGRAPH];
  __shared__ int hb[NBUCK];
  int b = blockIdx.x, t = threadIdx.x;

  if (b < BH_B) {
    for (int i = t; i < NBUCK; i += 256) hb[i] = 0;
    __syncthreads();
    int e0 = b * EPB, e1 = min(e0 + EPB, N_EDGESC);
    for (int e = e0 + t; e < e1; e += 256) atomicAdd(&hb[dst[e] >> 8], 1);
    __syncthreads();
    for (int i = t; i < NBUCK; i += 256) {
      int c = hb[i];
      hrow[b * NBUCK + i] = c;
      if (c) atomicAdd(&bcnt[i], c);
    }
    return;
  }
  b -= BH_B;
  if (b < XBF_B) {
    int idx = b * 256 + t;
    if (idx >= N_NODES * 24) return;
    int r = idx / 24, c = idx - r * 24;
    uint2 p = {0u, 0u};
    if (c < 21) {
      f32x4 v = *(const f32x4*)&x[r * DIN + c * 4];
      p.x = (unsigned int)f2bf(v.x) | ((unsigned int)f2bf(v.y) << 16);
      p.y = (unsigned int)f2bf(v.z) | ((unsigned int)f2bf(v.w) << 16);
    }
    *(uint2*)&xb[r * XSTR + c * 4] = p;
    return;
  }
  b -= XBF_B;
  if (b < W2T_B) {
    int idx = b * 256 + t;
    if (idx >= 896 * 96) return;
    int n = idx / 96, k = idx % 96;
    float v = (n < DHID && k < DIN) ? W2[k * DHID + n] : 0.f;
    w2t[idx] = f2bf(v);
    return;
  }
  b -= W2T_B;
  if (b < W1T_B) {
    int idx = b * 256 + t;
    if (idx >= 96 * 96) return;
    int n = idx / 96, k = idx % 96;
    float v = (n < DIN && k < DIN) ? W1[k * DIN + n] : 0.f;
    unsigned short hh = f2bf(v);
    w1h[idx] = hh;
    w1l[idx] = f2bf(v - bf2f(hh));
    return;
  }
  b -= W1T_B;
  if (b < CNT_B) {
    if (t < NGRAPH) h[t] = 0;
    __syncthreads();
    int base = b * 2048;
    for (int j = 0; j < 8; j++) {
      int i = base + j * 256 + t;
      if (i < N_NODES) atomicAdd(&h[batch[i]], 1);
    }
    __syncthreads();
    if (t < NGRAPH && h[t] > 0) atomicAdd(&cnt[t], h[t]);
    return;
  }
  b -= CNT_B;
  const float* W; unsigned short *wh, *wl; int K, KPAD, N, vb;
  if (b < G1_B) { W = Wg1; wh = g1h; wl = g1l; K = 2 * DHID; KPAD = KP1; N = DF1; vb = b; }
  else          { W = Wg2; wh = g2h; wl = g2l; K = DF1; KPAD = DF1; N = DOUTC; vb = b - G1_B; }
  int kt = vb % (KPAD / 32), nt2 = vb / (KPAD / 32);
  int k0 = kt * 32, n0 = nt2 * 32;
  int r = t >> 3, c4 = (t & 7) * 4;
  int k = k0 + r;
  f32x4 v = {0.f, 0.f, 0.f, 0.f};
  if (k < K) v = *(const f32x4*)&W[(size_t)k * N + n0 + c4];
  tile[r][c4 + 0] = v.x; tile[r][c4 + 1] = v.y; tile[r][c4 + 2] = v.z; tile[r][c4 + 3] = v.w;
  __syncthreads();
  int n = t >> 3;
  float f0 = tile[c4 + 0][n], f1 = tile[c4 + 1][n], f2 = tile[c4 + 2][n], f3 = tile[c4 + 3][n];
  unsigned short h0 = f2bf(f0), h1_ = f2bf(f1), h2_ = f2bf(f2), h3_ = f2bf(f3);
  uint2 ph, pl;
  ph.x = (unsigned int)h0 | ((unsigned int)h1_ << 16);
  ph.y = (unsigned int)h2_ | ((unsigned int)h3_ << 16);
  pl.x = (unsigned int)f2bf(f0 - bf2f(h0)) | ((unsigned int)f2bf(f1 - bf2f(h1_)) << 16);
  pl.y = (unsigned int)f2bf(f2 - bf2f(h2_)) | ((unsigned int)f2bf(f3 - bf2f(h3_)) << 16);
  *(uint2*)&wh[(size_t)(n0 + n) * KPAD + k0 + c4] = ph;
  *(uint2*)&wl[(size_t)(n0 + n) * KPAD + k0 + c4] = pl;
}

// ---------------- bcolscan: boff[g] = sum bcnt[<g]; hrow[blk][g] -> deterministic base ----
__global__ __launch_bounds__(512) void k_bcolscan(const int* __restrict__ bcnt, int* __restrict__ hrow,
                                                  int* __restrict__ boff) {
  __shared__ int sr[512];
  __shared__ int sd[512];
  int g = blockIdx.x, t = threadIdx.x;
  sr[t] = (t < g) ? bcnt[t] : 0;
  __syncthreads();
  for (int off = 256; off > 0; off >>= 1) {
    if (t < off) sr[t] += sr[t + off];
    __syncthreads();
  }
  int base0 = sr[0];
  if (t == 0) boff[g] = base0;
  if (g == 0 && t == 0) boff[NBUCK] = N_EDGESC;
  int v = (t < EBLK) ? hrow[t * NBUCK + g] : 0;
  sd[t] = v;
  __syncthreads();
  for (int off = 1; off < 512; off <<= 1) {
    int add = (t >= off) ? sd[t - off] : 0;
    __syncthreads();
    sd[t] += add;
    __syncthreads();
  }
  if (t < EBLK) hrow[t * NBUCK + g] = base0 + sd[t] - v;   // exclusive base
}

// ---------------- bfill2: single edge pass, deterministic bases, no global atomics --------
__global__ __launch_bounds__(256) void k_bfill2(const int* __restrict__ src, const int* __restrict__ dst,
                                                const int* __restrict__ hrow, unsigned int* __restrict__ rec) {
  __shared__ int hcnt[NBUCK];
  __shared__ int hbase[NBUCK];
  int t = threadIdx.x, b = blockIdx.x;
  for (int i = t; i < NBUCK; i += 256) { hcnt[i] = 0; hbase[i] = hrow[b * NBUCK + i]; }
  __syncthreads();
  int e0 = b * EPB, e1 = min(e0 + EPB, N_EDGESC);
  for (int e = e0 + t; e < e1; e += 256) {
    int d = dst[e];
    int bk = d >> 8;
    int r = atomicAdd(&hcnt[bk], 1);
    rec[hbase[bk] + r] = ((unsigned int)(d & 255) << 24) | (unsigned int)src[e];
  }
}

__global__ __launch_bounds__(256) void k_bsort(const unsigned int* __restrict__ rec, const int* __restrict__ boff,
                                               int* __restrict__ rowptr, int* __restrict__ csr) {
  __shared__ int lcnt[256];
  __shared__ int lcur[256];
  int b = blockIdx.x, t = threadIdx.x;
  int e0 = boff[b], e1 = boff[b + 1];
  lcnt[t] = 0;
  __syncthreads();
  for (int i = e0 + t; i < e1; i += 256) atomicAdd(&lcnt[rec[i] >> 24], 1);
  __syncthreads();
  int v = lcnt[t];
  for (int off = 1; off < 256; off <<= 1) {
    int add = (t >= off) ? lcnt[t - off] : 0;
    __syncthreads();
    lcnt[t] += add;
    __syncthreads();
  }
  int excl = lcnt[t] - v;
  int node = b * 256 + t;
  if (node < N_NODES) rowptr[node] = e0 + excl;
  lcur[t] = e0 + excl;
  if (b == NBUCK - 1 && t == 0) rowptr[N_NODES] = N_EDGESC;
  __syncthreads();
  for (int i = e0 + t; i < e1; i += 256) {
    unsigned int r = rec[i];
    int d = r >> 24;
    int pos = atomicAdd(&lcur[d], 1);
    csr[pos] = (int)(r & 0xFFFFFFu);
  }
}

// ---------------- agg1c: predicated 8-wide gather batches -> bf16 out (stride 96) --------
// Every batch issues 8 loads (indices clamped in-bounds); invalid lanes add exact 0.0f.
// Eliminates the serial scalar tail (deg mod 4 edges) from the latency critical path.
__global__ __launch_bounds__(256) void k_agg1c(const unsigned short* __restrict__ xb,
                                               const int* __restrict__ rowptr,
                                               const int* __restrict__ csr,
                                               unsigned short* __restrict__ aggh) {
  int t = threadIdx.x;
  int wv = t >> 6, l = t & 63;
  int grp = (l >= 42) ? 2 : (l >= 21 ? 1 : 0);
  int li = l - grp * 21;
  int node = blockIdx.x * 12 + wv * 3 + grp;
  bool act = (li < 21) && (node < N_NODES);
  if (l == 63) {
    uint2 z = {0u, 0u};
    for (int g = 0; g < 3; g++) {
      int nd = blockIdx.x * 12 + wv * 3 + g;
      if (nd < N_NODES) {
        *(uint2*)&aggh[nd * XSTR + 84] = z; *(uint2*)&aggh[nd * XSTR + 88] = z; *(uint2*)&aggh[nd * XSTR + 92] = z;
      }
    }
  }
  int nclamp = min(node, N_NODES - 1);
  int r0 = rowptr[nclamp];
  int r1 = act ? rowptr[nclamp + 1] : r0;
  f32x4 a = {0.f, 0.f, 0.f, 0.f};
  if (act) a = bfq(*(const uint2*)&xb[nclamp * XSTR + li * 4]);
  const f32x4 z4 = {0.f, 0.f, 0.f, 0.f};
  int eN = r1 - 1;
  for (int e = r0; e < r1; e += 8) {
    int i1 = min(e + 1, eN), i2 = min(e + 2, eN), i3 = min(e + 3, eN);
    int i4 = min(e + 4, eN), i5 = min(e + 5, eN), i6 = min(e + 6, eN), i7 = min(e + 7, eN);
    int s0 = csr[e],  s1 = csr[i1], s2 = csr[i2], s3 = csr[i3];
    int s4 = csr[i4], s5 = csr[i5], s6 = csr[i6], s7 = csr[i7];
    uint2 q0 = *(const uint2*)&xb[s0 * XSTR + li * 4];
    uint2 q1 = *(const uint2*)&xb[s1 * XSTR + li * 4];
    uint2 q2 = *(const uint2*)&xb[s2 * XSTR + li * 4];
    uint2 q3 = *(const uint2*)&xb[s3 * XSTR + li * 4];
    uint2 q4 = *(const uint2*)&xb[s4 * XSTR + li * 4];
    uint2 q5 = *(const uint2*)&xb[s5 * XSTR + li * 4];
    uint2 q6 = *(const uint2*)&xb[s6 * XSTR + li * 4];
    uint2 q7 = *(const uint2*)&xb[s7 * XSTR + li * 4];
    f32x4 v0 = bfq(q0);
    f32x4 v1 = (e + 1 < r1) ? bfq(q1) : z4;
    f32x4 v2 = (e + 2 < r1) ? bfq(q2) : z4;
    f32x4 v3 = (e + 3 < r1) ? bfq(q3) : z4;
    f32x4 v4 = (e + 4 < r1) ? bfq(q4) : z4;
    f32x4 v5 = (e + 5 < r1) ? bfq(q5) : z4;
    f32x4 v6 = (e + 6 < r1) ? bfq(q6) : z4;
    f32x4 v7 = (e + 7 < r1) ? bfq(q7) : z4;
    a += ((v0 + v1) + (v2 + v3)) + ((v4 + v5) + (v6 + v7));
  }
  if (act) {
    uint2 p;
    p.x = (unsigned int)f2bf(a.x) | ((unsigned int)f2bf(a.y) << 16);
    p.y = (unsigned int)f2bf(a.z) | ((unsigned int)f2bf(a.w) << 16);
    *(uint2*)&aggh[node * XSTR + li * 4] = p;
  }
}

// ---------------- conv1m2: MFMA from global bf16 A (no LDS), split W1, h1b bf16 out -------
__global__ __launch_bounds__(256) void k_conv1m2(const unsigned short* __restrict__ aggh,
                                                 const unsigned short* __restrict__ w1h,
                                                 const unsigned short* __restrict__ w1l,
                                                 const float* __restrict__ b1,
                                                 unsigned short* __restrict__ h1b) {
  int t = threadIdx.x;
  int m0 = blockIdx.x * 64;
  int wv = t >> 6, l = t & 63;
  int lr = l & 15, lk = (l >> 4) * 8;
  int row = m0 + wv * 16 + lr;
  bool inb = row < N_NODES;
  bf16x8 ah[3];
  #pragma unroll
  for (int kk = 0; kk < 3; kk++) {
    bf16x8 vh = {0, 0, 0, 0, 0, 0, 0, 0};
    if (inb) vh = *(const bf16x8*)&aggh[(size_t)row * XSTR + lk + kk * 32];
    ah[kk] = vh;
  }
  #pragma unroll
  for (int nt = 0; nt < 6; nt++) {
    f32x4 acc = {0.f, 0.f, 0.f, 0.f};
    #pragma unroll
    for (int kk = 0; kk < 3; kk++) {
      bf16x8 bh = *(const bf16x8*)&w1h[(nt * 16 + lr) * 96 + lk + kk * 32];
      bf16x8 bl = *(const bf16x8*)&w1l[(nt * 16 + lr) * 96 + lk + kk * 32];
      acc = __builtin_amdgcn_mfma_f32_16x16x32_bf16(ah[kk], bh, acc, 0, 0, 0);
      acc = __builtin_amdgcn_mfma_f32_16x16x32_bf16(ah[kk], bl, acc, 0, 0, 0);
    }
    int col = nt * 16 + lr;
    if (col < DIN) {
      float bias = b1[col];
      int rbase = m0 + wv * 16 + (l >> 4) * 4;
      #pragma unroll
      for (int j = 0; j < 4; j++) {
        if (rbase + j < N_NODES)
          h1b[(rbase + j) * XSTR + col] = f2bf(fmaxf(acc[j] + bias, 0.f));
      }
    }
  }
}

// ---------------- agg2: predicated 8-wide gather, bf16 out cols 0..83 (stride 96) --------
__global__ __launch_bounds__(256) void k_agg2(const unsigned short* __restrict__ h1b, const int* __restrict__ rowptr,
                                              const int* __restrict__ csr, unsigned short* __restrict__ out) {
  int t = threadIdx.x;
  int wv = t >> 6, l = t & 63;
  int grp = (l >= 42) ? 2 : (l >= 21 ? 1 : 0);
  int li = l - grp * 21;
  int node = blockIdx.x * 12 + wv * 3 + grp;
  bool act = (li < 21) && (node < N_NODES);
  int nclamp = min(node, N_NODES - 1);
  int r0 = rowptr[nclamp];
  int r1 = act ? rowptr[nclamp + 1] : r0;
  f32x4 a = {0.f, 0.f, 0.f, 0.f};
  if (act) a = bfq(*(const uint2*)&h1b[nclamp * XSTR + li * 4]);
  const f32x4 z4 = {0.f, 0.f, 0.f, 0.f};
  int eN = r1 - 1;
  for (int e = r0; e < r1; e += 8) {
    int i1 = min(e + 1, eN), i2 = min(e + 2, eN), i3 = min(e + 3, eN);
    int i4 = min(e + 4, eN), i5 = min(e + 5, eN), i6 = min(e + 6, eN), i7 = min(e + 7, eN);
    int s0 = csr[e],  s1 = csr[i1], s2 = csr[i2], s3 = csr[i3];
    int s4 = csr[i4], s5 = csr[i5], s6 = csr[i6], s7 = csr[i7];
    uint2 q0 = *(const uint2*)&h1b[s0 * XSTR + li * 4];
    uint2 q1 = *(const uint2*)&h1b[s1 * XSTR + li * 4];
    uint2 q2 = *(const uint2*)&h1b[s2 * XSTR + li * 4];
    uint2 q3 = *(const uint2*)&h1b[s3 * XSTR + li * 4];
    uint2 q4 = *(const uint2*)&h1b[s4 * XSTR + li * 4];
    uint2 q5 = *(const uint2*)&h1b[s5 * XSTR + li * 4];
    uint2 q6 = *(const uint2*)&h1b[s6 * XSTR + li * 4];
    uint2 q7 = *(const uint2*)&h1b[s7 * XSTR + li * 4];
    f32x4 v0 = bfq(q0);
    f32x4 v1 = (e + 1 < r1) ? bfq(q1) : z4;
    f32x4 v2 = (e + 2 < r1) ? bfq(q2) : z4;
    f32x4 v3 = (e + 3 < r1) ? bfq(q3) : z4;
    f32x4 v4 = (e + 4 < r1) ? bfq(q4) : z4;
    f32x4 v5 = (e + 5 < r1) ? bfq(q5) : z4;
    f32x4 v6 = (e + 6 < r1) ? bfq(q6) : z4;
    f32x4 v7 = (e + 7 < r1) ? bfq(q7) : z4;
    a += ((v0 + v1) + (v2 + v3)) + ((v4 + v5) + (v6 + v7));
  }
  if (act) {
    uint2 p;
    p.x = (unsigned int)f2bf(a.x) | ((unsigned int)f2bf(a.y) << 16);
    p.y = (unsigned int)f2bf(a.z) | ((unsigned int)f2bf(a.w) << 16);
    *(uint2*)&out[node * XSTR + li * 4] = p;
  }
}

// ---------------- conv2 + pooling stage 1: 64-row tiles x 2 column-halves ----------------
__global__ __launch_bounds__(256) void k_conv2pool4(const unsigned short* __restrict__ aggb,
                                                    const unsigned short* __restrict__ w2t,
                                                    const float* __restrict__ b2,
                                                    const int* __restrict__ batch,
                                                    float2* __restrict__ pm, float2* __restrict__ pm1,
                                                    int* __restrict__ blkg,
                                                    int* __restrict__ maxb, float* __restrict__ sump) {
  constexpr int LDA = 104;
  __shared__ __align__(16) unsigned short At[64 * LDA];
  int t = threadIdx.x;
  int w = t >> 6, l = t & 63;
  int b = blockIdx.x >> 1;
  int half = blockIdx.x & 1;
  int m0 = b * 64;
  int lr = l & 15, hi = l >> 4, lk = hi * 8;

  for (int idx = t; idx < 64 * 12; idx += 256) {
    int r = idx / 12, c = idx - r * 12;
    uint4 v = {0u, 0u, 0u, 0u};
    int row = m0 + r;
    if (row < N_NODES) v = *(const uint4*)&aggb[row * XSTR + c * 8];
    *(uint4*)&At[r * LDA + c * 8] = v;
  }
  int g0 = batch[m0];
  int g1 = batch[min(m0 + 63, N_NODES - 1)];
  bool fast = (g0 == g1) && (m0 + 63 < N_NODES);
  __syncthreads();

  bf16x8 afr[4][3];
  #pragma unroll
  for (int rg = 0; rg < 4; rg++)
    #pragma unroll
    for (int kk = 0; kk < 3; kk++)
      afr[rg][kk] = *(bf16x8*)&At[(rg * 16 + lr) * LDA + lk + kk * 32];

  int pbase = half * 28 + w * 7;

  if (fast) {
    for (int i = 0; i < 7; i++) {
      int c = (pbase + i) * 16 + lr;
      const unsigned short* bp = &w2t[c * 96 + lk];
      bf16x8 b0v = *(const bf16x8*)(bp);
      bf16x8 b1v = *(const bf16x8*)(bp + 32);
      bf16x8 b2v = *(const bf16x8*)(bp + 64);
      float bias = (c < DHID) ? b2[c] : 0.f;
      float mx = 0.f, sm = 0.f;
      #pragma unroll
      for (int rg = 0; rg < 4; rg++) {
        f32x4 a_ = {0.f, 0.f, 0.f, 0.f};
        a_ = __builtin_amdgcn_mfma_f32_16x16x32_bf16(afr[rg][0], b0v, a_, 0, 0, 0);
        a_ = __builtin_amdgcn_mfma_f32_16x16x32_bf16(afr[rg][1], b1v, a_, 0, 0, 0);
        a_ = __builtin_amdgcn_mfma_f32_16x16x32_bf16(afr[rg][2], b2v, a_, 0, 0, 0);
        float v0 = fmaxf(a_[0] + bias, 0.f);
        float v1 = fmaxf(a_[1] + bias, 0.f);
        float v2 = fmaxf(a_[2] + bias, 0.f);
        float v3 = fmaxf(a_[3] + bias, 0.f);
        mx = fmaxf(mx, fmaxf(fmaxf(v0, v1), fmaxf(v2, v3)));
        sm += (v0 + v1) + (v2 + v3);
      }
      mx = fmaxf(mx, __shfl_xor(mx, 16)); sm += __shfl_xor(sm, 16);
      mx = fmaxf(mx, __shfl_xor(mx, 32)); sm += __shfl_xor(sm, 32);
      if (hi == 0 && c < DHID) pm[(size_t)b * DHID + c] = make_float2(mx, sm);
    }
  } else {
    int grow[4][4];
    #pragma unroll
    for (int rg = 0; rg < 4; rg++)
      #pragma unroll
      for (int j = 0; j < 4; j++) {
        int row = m0 + rg * 16 + hi * 4 + j;
        grow[rg][j] = (row < N_NODES) ? batch[row] : -1;
      }
    for (int i = 0; i < 7; i++) {
      int c = (pbase + i) * 16 + lr;
      const unsigned short* bp = &w2t[c * 96 + lk];
      bf16x8 b0v = *(const bf16x8*)(bp);
      bf16x8 b1v = *(const bf16x8*)(bp + 32);
      bf16x8 b2v = *(const bf16x8*)(bp + 64);
      float bias = (c < DHID) ? b2[c] : 0.f;
      float mx0 = 0.f, sm0 = 0.f, mx1 = 0.f, sm1 = 0.f;
      float vv[4][4];
      #pragma unroll
      for (int rg = 0; rg < 4; rg++) {
        f32x4 a_ = {0.f, 0.f, 0.f, 0.f};
        a_ = __builtin_amdgcn_mfma_f32_16x16x32_bf16(afr[rg][0], b0v, a_, 0, 0, 0);
        a_ = __builtin_amdgcn_mfma_f32_16x16x32_bf16(afr[rg][1], b1v, a_, 0, 0, 0);
        a_ = __builtin_amdgcn_mfma_f32_16x16x32_bf16(afr[rg][2], b2v, a_, 0, 0, 0);
        #pragma unroll
        for (int j = 0; j < 4; j++) {
          float v = fmaxf(a_[j] + bias, 0.f);
          vv[rg][j] = v;
          if (grow[rg][j] == g0) { mx0 = fmaxf(mx0, v); sm0 += v; }
          if (grow[rg][j] == g1) { mx1 = fmaxf(mx1, v); sm1 += v; }
        }
      }
      mx0 = fmaxf(mx0, __shfl_xor(mx0, 16)); sm0 += __shfl_xor(sm0, 16);
      mx0 = fmaxf(mx0, __shfl_xor(mx0, 32)); sm0 += __shfl_xor(sm0, 32);
      mx1 = fmaxf(mx1, __shfl_xor(mx1, 16)); sm1 += __shfl_xor(sm1, 16);
      mx1 = fmaxf(mx1, __shfl_xor(mx1, 32)); sm1 += __shfl_xor(sm1, 32);
      if (hi == 0 && c < DHID) {
        pm[(size_t)b * DHID + c] = make_float2(mx0, sm0);
        pm1[(size_t)b * DHID + c] = make_float2(mx1, sm1);
      }
      if (g1 - g0 >= 2) {
        for (int g = g0 + 1; g < g1; g++) {
          float mx = 0.f, sm = 0.f;
          #pragma unroll
          for (int rg = 0; rg < 4; rg++)
            #pragma unroll
            for (int j = 0; j < 4; j++)
              if (grow[rg][j] == g) { mx = fmaxf(mx, vv[rg][j]); sm += vv[rg][j]; }
          mx = fmaxf(mx, __shfl_xor(mx, 16)); sm += __shfl_xor(sm, 16);
          mx = fmaxf(mx, __shfl_xor(mx, 32)); sm += __shfl_xor(sm, 32);
          if (hi == 0 && c < DHID) {
            atomicMax(&maxb[g * DHID + c], __float_as_int(mx));
            atomicAdd(&sump[g * DHID + c], sm);
          }
        }
      }
    }
  }
  if (t == 0 && half == 0) { blkg[b * 2] = g0; blkg[b * 2 + 1] = g1; }
}

// ---------------- pooling stage 2: merge partials, emit z as hi/lo bf16 [128][KP1] --------
__global__ __launch_bounds__(256) void k_pool2(const float2* __restrict__ pm, const float2* __restrict__ pm1,
                                               const int* __restrict__ blkg, const int* __restrict__ cnt,
                                               const int* __restrict__ maxb, const float* __restrict__ sump,
                                               unsigned short* __restrict__ zh, unsigned short* __restrict__ zl) {
  __shared__ int sstart[NGRAPH];
  int g = blockIdx.x, t = threadIdx.x;
  if (t == 0) {
    int s = 0;
    for (int i = 0; i < NGRAPH; i++) { sstart[i] = s; s += cnt[i]; }
  }
  __syncthreads();
  int c0 = cnt[g];
  int ns = sstart[g], ne = ns + c0;
  int b0 = ns / 64, b1 = (c0 > 0) ? (ne - 1) / 64 : b0 - 1;
  for (int c = t; c < DHID; c += 256) {
    float mx = __int_as_float(maxb[g * DHID + c]);
    float sm = sump[g * DHID + c];
    for (int b = b0; b <= b1; b++) {
      int gg0 = blkg[2 * b], gg1 = blkg[2 * b + 1];
      if (gg0 == g)      { float2 p = pm[(size_t)b * DHID + c];  mx = fmaxf(mx, p.x); sm += p.y; }
      else if (gg1 == g) { float2 p = pm1[(size_t)b * DHID + c]; mx = fmaxf(mx, p.x); sm += p.y; }
    }
    float vmax = (c0 > 0) ? mx : 0.f;
    float vmean = sm / (float)max(c0, 1);
    unsigned short hm = f2bf(vmax);
    zh[g * KP1 + c] = hm;
    zl[g * KP1 + c] = f2bf(vmax - bf2f(hm));
    unsigned short he = f2bf(vmean);
    zh[g * KP1 + DHID + c] = he;
    zl[g * KP1 + DHID + c] = f2bf(vmean - bf2f(he));
  }
  if (t < KP1 - 2 * DHID) {
    zh[g * KP1 + 2 * DHID + t] = 0;
    zl[g * KP1 + 2 * DHID + t] = 0;
  }
}

// ---------------- MLP1: z1 = relu(z @ Wg1 + bg1), split-bf16 MFMA, hi/lo out ----------------
__global__ __launch_bounds__(256) void k_mlp1m(const unsigned short* __restrict__ zh, const unsigned short* __restrict__ zl,
                                               const unsigned short* __restrict__ wh, const unsigned short* __restrict__ wl,
                                               const float* __restrict__ bg,
                                               unsigned short* __restrict__ z1h, unsigned short* __restrict__ z1l) {
  int t = threadIdx.x, w = t >> 6, l = t & 63;
  int lr = l & 15, hi = l >> 4, lk = hi * 8;
  int b = blockIdx.x;
  int n0 = (b >> 1) * 16;
  int m0 = (b & 1) * 64 + w * 16;
  const unsigned short* za = &zh[(size_t)(m0 + lr) * KP1 + lk];
  const unsigned short* zb = &zl[(size_t)(m0 + lr) * KP1 + lk];
  const unsigned short* wa = &wh[(size_t)(n0 + lr) * KP1 + lk];
  const unsigned short* wb = &wl[(size_t)(n0 + lr) * KP1 + lk];
  f32x4 acc = {0.f, 0.f, 0.f, 0.f};
  for (int ks = 0; ks < KP1 / 32; ks++) {
    bf16x8 ah = *(const bf16x8*)(za + ks * 32);
    bf16x8 al = *(const bf16x8*)(zb + ks * 32);
    bf16x8 bh = *(const bf16x8*)(wa + ks * 32);
    bf16x8 bl = *(const bf16x8*)(wb + ks * 32);
    acc = __builtin_amdgcn_mfma_f32_16x16x32_bf16(ah, bh, acc, 0, 0, 0);
    acc = __builtin_amdgcn_mfma_f32_16x16x32_bf16(al, bh, acc, 0, 0, 0);
    acc = __builtin_amdgcn_mfma_f32_16x16x32_bf16(ah, bl, acc, 0, 0, 0);
  }
  int col = n0 + lr;
  float bias = bg[col];
  #pragma unroll
  for (int j = 0; j < 4; j++) {
    int row = m0 + hi * 4 + j;
    float v = fmaxf(acc[j] + bias, 0.f);
    unsigned short h = f2bf(v);
    z1h[row * DF1 + col] = h;
    z1l[row * DF1 + col] = f2bf(v - bf2f(h));
  }
}

// ---------------- MLP2: out = z1 @ Wg2 + bg2, split-bf16 MFMA, f32 out ----------------
__global__ __launch_bounds__(256) void k_mlp2m(const unsigned short* __restrict__ z1h, const unsigned short* __restrict__ z1l,
                                               const unsigned short* __restrict__ wh, const unsigned short* __restrict__ wl,
                                               const float* __restrict__ bg, float* __restrict__ out) {
  int t = threadIdx.x, w = t >> 6, l = t & 63;
  int lr = l & 15, hi = l >> 4, lk = hi * 8;
  int b = blockIdx.x;
  int n0 = (b >> 1) * 16;
  int m0 = (b & 1) * 64 + w * 16;
  const unsigned short* za = &z1h[(size_t)(m0 + lr) * DF1 + lk];
  const unsigned short* zb = &z1l[(size_t)(m0 + lr) * DF1 + lk];
  const unsigned short* wa = &wh[(size_t)(n0 + lr) * DF1 + lk];
  const unsigned short* wb = &wl[(size_t)(n0 + lr) * DF1 + lk];
  f32x4 acc = {0.f, 0.f, 0.f, 0.f};
  for (int ks = 0; ks < DF1 / 32; ks++) {
    bf16x8 ah = *(const bf16x8*)(za + ks * 32);
    bf16x8 al = *(const bf16x8*)(zb + ks * 32);
    bf16x8 bh = *(const bf16x8*)(wa + ks * 32);
    bf16x8 bl = *(const bf16x8*)(wb + ks * 32);
    acc = __builtin_amdgcn_mfma_f32_16x16x32_bf16(ah, bh, acc, 0, 0, 0);
    acc = __builtin_amdgcn_mfma_f32_16x16x32_bf16(al, bh, acc, 0, 0, 0);
    acc = __builtin_amdgcn_mfma_f32_16x16x32_bf16(ah, bl, acc, 0, 0, 0);
  }
  int col = n0 + lr;
  float bias = bg[col];
  #pragma unroll
  for (int j = 0; j < 4; j++) {
    int row = m0 + hi * 4 + j;
    out[row * DOUTC + col] = acc[j] + bias;
  }
}

// ---------------- launch ----------------
static constexpr size_t AL(size_t x) { return (x + 255) & ~(size_t)255; }

extern "C" void kernel_launch(void* const* d_in, const int* in_sizes, int n_in,
                              void* d_out, int out_size, void* d_ws, size_t ws_size,
                              hipStream_t stream) {
  const float* x   = (const float*)d_in[0];
  const int*  edge = (const int*)d_in[1];
  const int*  batch= (const int*)d_in[2];
  const float* W1  = (const float*)d_in[3];
  const float* b1  = (const float*)d_in[4];
  const float* W2  = (const float*)d_in[5];
  const float* b2  = (const float*)d_in[6];
  const float* Wg1 = (const float*)d_in[7];
  const float* bg1 = (const float*)d_in[8];
  const float* Wg2 = (const float*)d_in[9];
  const float* bg2 = (const float*)d_in[10];
  float* out = (float*)d_out;
  const int* src = edge;
  const int* dst = edge + N_EDGESC;

  size_t o = 0;
  size_t OFF_AGG = o;  o += AL((size_t)N_NODES * DIN * 4);    // pooling partials scratch
  size_t OFF_AGH = o;  o += AL((size_t)N_NODES * XSTR * 2);   // aggh bf16
  size_t OFF_H1  = o;  o += AL((size_t)N_NODES * XSTR * 2);   // h1b bf16, stride 96
  size_t OFF_AGB = o;  o += AL((size_t)N_NODES * XSTR * 2);   // xb then aggb (both stride 96)
  size_t OFF_CSR = o;  o += AL((size_t)N_EDGESC * 4);
  size_t OFF_REC = o;  o += AL((size_t)N_EDGESC * 4);
  size_t OFF_HRW = o;  o += AL((size_t)EBLK * NBUCK * 4);     // per-block bucket hist -> bases
  size_t OFF_W2T = o;  o += AL((size_t)896 * 96 * 2);
  size_t OFF_W1H = o;  o += AL((size_t)96 * 96 * 2);
  size_t OFF_W1L = o;  o += AL((size_t)96 * 96 * 2);
  size_t OFF_G1H = o;  o += AL((size_t)DF1 * KP1 * 2);
  size_t OFF_G1L = o;  o += AL((size_t)DF1 * KP1 * 2);
  size_t OFF_G2H = o;  o += AL((size_t)DOUTC * DF1 * 2);
  size_t OFF_G2L = o;  o += AL((size_t)DOUTC * DF1 * 2);
  size_t OFF_ZH  = o;  o += AL((size_t)NGRAPH * KP1 * 2);
  size_t OFF_ZL  = o;  o += AL((size_t)NGRAPH * KP1 * 2);
  size_t OFF_Z1H = o;  o += AL((size_t)NGRAPH * DF1 * 2);
  size_t OFF_Z1L = o;  o += AL((size_t)NGRAPH * DF1 * 2);
  size_t OFF_RP  = o;  o += AL((size_t)(N_NODES + 1) * 4);
  size_t OFF_BOF = o;  o += AL((NBUCK + 1) * 4);
  size_t OFF_BC  = o;  o += AL(NBUCK * 4);                    // zero region starts here
  size_t OFF_MAX = o;  o += AL((size_t)NGRAPH * DHID * 4);
  size_t OFF_SUM = o;  o += AL((size_t)NGRAPH * DHID * 4);
  size_t OFF_CNT = o;  o += AL(NGRAPH * 4);
  size_t TOTAL = o;
  size_t ZERO0 = OFF_BC, ZEROB = TOTAL - OFF_BC;
  if (ws_size < TOTAL) return;

  size_t PB = AL((size_t)PBLK3 * DHID * 8);
  size_t OFF_PM  = OFF_AGG;   // pm/pm1 alias the 33.6MB agg-scratch region
  size_t OFF_PM1 = OFF_AGG + PB;
  size_t OFF_BLG = OFF_AGG + 2 * PB;

  char* ws = (char*)d_ws;
  unsigned short* aggh = (unsigned short*)(ws + OFF_AGH);
  unsigned short* h1b = (unsigned short*)(ws + OFF_H1);
  unsigned short* aggb = (unsigned short*)(ws + OFF_AGB);
  unsigned short* xb   = (unsigned short*)(ws + OFF_AGB);   // alias: xb dead before aggb written
  int* csr   = (int*)(ws + OFF_CSR);
  unsigned int* rec = (unsigned int*)(ws + OFF_REC);
  int* hrow  = (int*)(ws + OFF_HRW);
  unsigned short* w2t = (unsigned short*)(ws + OFF_W2T);
  unsigned short* w1h = (unsigned short*)(ws + OFF_W1H);
  unsigned short* w1l = (unsigned short*)(ws + OFF_W1L);
  unsigned short* g1h = (unsigned short*)(ws + OFF_G1H);
  unsigned short* g1l = (unsigned short*)(ws + OFF_G1L);
  unsigned short* g2h = (unsigned short*)(ws + OFF_G2H);
  unsigned short* g2l = (unsigned short*)(ws + OFF_G2L);
  unsigned short* zh  = (unsigned short*)(ws + OFF_ZH);
  unsigned short* zl  = (unsigned short*)(ws + OFF_ZL);
  unsigned short* z1h = (unsigned short*)(ws + OFF_Z1H);
  unsigned short* z1l = (unsigned short*)(ws + OFF_Z1L);
  int* rowptr = (int*)(ws + OFF_RP);
  int* boff  = (int*)(ws + OFF_BOF);
  int* bcnt  = (int*)(ws + OFF_BC);
  int* maxb  = (int*)(ws + OFF_MAX);
  float* sump= (float*)(ws + OFF_SUM);
  int* cnt   = (int*)(ws + OFF_CNT);
  float2* pm  = (float2*)(ws + OFF_PM);
  float2* pm1 = (float2*)(ws + OFF_PM1);
  int* blkg  = (int*)(ws + OFF_BLG);

  hipMemsetAsync(ws + ZERO0, 0, ZEROB, stream);

  k_prep<<<PREP_B, 256, 0, stream>>>(dst, hrow, bcnt, x, xb, W2, w2t, W1, w1h, w1l,
                                     batch, cnt, Wg1, g1h, g1l, Wg2, g2h, g2l);
  k_bcolscan<<<NBUCK, 512, 0, stream>>>(bcnt, hrow, boff);
  k_bfill2<<<EBLK, 256, 0, stream>>>(src, dst, hrow, rec);
  k_bsort<<<NBUCK, 256, 0, stream>>>(rec, boff, rowptr, csr);

  k_agg1c<<<(N_NODES + 11) / 12, 256, 0, stream>>>(xb, rowptr, csr, aggh);
  k_conv1m2<<<PBLK3, 256, 0, stream>>>(aggh, w1h, w1l, b1, h1b);
  k_agg2<<<(N_NODES + 11) / 12, 256, 0, stream>>>(h1b, rowptr, csr, aggb);
  k_conv2pool4<<<2 * PBLK3, 256, 0, stream>>>(aggb, w2t, b2, batch, pm, pm1, blkg, maxb, sump);
  k_pool2<<<NGRAPH, 256, 0, stream>>>(pm, pm1, blkg, cnt, maxb, sump, zh, zl);

  k_mlp1m<<<(DF1 / 16) * 2, 256, 0, stream>>>(zh, zl, g1h, g1l, bg1, z1h, z1l);
  k_mlp2m<<<(DOUTC / 16) * 2, 256, 0, stream>>>(z1h, z1l, g2h, g2l, bg2, out);
}